// Round 2
// baseline (2011.424 us; speedup 1.0000x reference)
//
#include <hip/hip_runtime.h>

typedef unsigned int u32;
typedef unsigned short u16;
typedef float f32x4 __attribute__((ext_vector_type(4)));
typedef u16 us4 __attribute__((ext_vector_type(4)));
typedef u16 us8 __attribute__((ext_vector_type(8)));
typedef __bf16 bf16x8 __attribute__((ext_vector_type(8)));

__device__ __forceinline__ u16 f2bf(float f) {
  u32 u = __builtin_bit_cast(u32, f);
  u += 0x7fffu + ((u >> 16) & 1u);
  return (u16)(u >> 16);
}
__device__ __forceinline__ float bf2f(u16 h) {
  u32 u = ((u32)h) << 16;
  return __builtin_bit_cast(float, u);
}
__device__ __forceinline__ void async16(const void* g, void* l) {
  __builtin_amdgcn_global_load_lds((const __attribute__((address_space(1))) void*)g,
                                   (__attribute__((address_space(3))) void*)l, 16, 0, 0);
}

// ---------------------------------------------------------------------------
// C = A * B^T.  A: M x K bf16 row-major. B: N x K bf16 row-major. C: M x N
// (row stride ldc), fp32 or bf16.  M,N multiples of 128; K multiple of 32.
// m97 structure: 128x128 tile, BK=32, global_load_lds width 16, 4 waves with
// 4x4 16x16x32 MFMA fragments each.
// ---------------------------------------------------------------------------
template <bool BF16OUT>
__global__ __launch_bounds__(256) void gemm_bt(const u16* __restrict__ A,
                                               const u16* __restrict__ B,
                                               void* __restrict__ Cv,
                                               int K, int ldc) {
  __shared__ __align__(16) u16 As[128 * 32];
  __shared__ __align__(16) u16 Bs[128 * 32];
  const int tid = threadIdx.x;
  const int lane = tid & 63;
  const int wave = tid >> 6;
  const int lm = lane & 15;
  const int quad = lane >> 4;
  const int wm = (wave >> 1) << 6;  // wave M offset (0/64)
  const int wn = (wave & 1) << 6;   // wave N offset (0/64)
  const long rowBase = (long)blockIdx.y << 7;
  const long colBase = (long)blockIdx.x << 7;

  // staging: chunk c = tid (+256); row = c>>2, col = (c&3)*8 (16B chunks)
  const int r0 = tid >> 2;
  const int cc0 = (tid & 3) << 3;
  const u16* Ag0 = A + (rowBase + r0) * (long)K + cc0;
  const u16* Ag1 = Ag0 + 64L * K;
  const u16* Bg0 = B + (colBase + r0) * (long)K + cc0;
  const u16* Bg1 = Bg0 + 64L * K;
  u16* Al0 = As + tid * 8;
  u16* Al1 = As + (tid + 256) * 8;
  u16* Bl0 = Bs + tid * 8;
  u16* Bl1 = Bs + (tid + 256) * 8;

  f32x4 acc[4][4] = {};

  for (int k0 = 0; k0 < K; k0 += 32) {
    async16(Ag0 + k0, Al0);
    async16(Ag1 + k0, Al1);
    async16(Bg0 + k0, Bl0);
    async16(Bg1 + k0, Bl1);
    __syncthreads();
    us8 af[4], bfr[4];
#pragma unroll
    for (int i = 0; i < 4; ++i)
      af[i] = *(const us8*)(As + (wm + i * 16 + lm) * 32 + quad * 8);
#pragma unroll
    for (int i = 0; i < 4; ++i)
      bfr[i] = *(const us8*)(Bs + (wn + i * 16 + lm) * 32 + quad * 8);
#pragma unroll
    for (int i = 0; i < 4; ++i)
#pragma unroll
      for (int j = 0; j < 4; ++j)
        acc[i][j] = __builtin_amdgcn_mfma_f32_16x16x32_bf16(
            __builtin_bit_cast(bf16x8, af[i]), __builtin_bit_cast(bf16x8, bfr[j]),
            acc[i][j], 0, 0, 0);
    __syncthreads();
  }

#pragma unroll
  for (int i = 0; i < 4; ++i)
#pragma unroll
    for (int j = 0; j < 4; ++j)
#pragma unroll
      for (int r = 0; r < 4; ++r) {
        long row = rowBase + wm + i * 16 + quad * 4 + r;
        long col = colBase + wn + j * 16 + lm;
        if constexpr (BF16OUT)
          ((u16*)Cv)[row * ldc + col] = f2bf(acc[i][j][r]);
        else
          ((float*)Cv)[row * ldc + col] = acc[i][j][r];
      }
}

// fp32 -> bf16, 4 elems/thread
__global__ __launch_bounds__(256) void cvt_bf16(const float* __restrict__ in,
                                                u16* __restrict__ out, int n4) {
  int i = blockIdx.x * 256 + threadIdx.x;
  if (i >= n4) return;
  f32x4 v = ((const f32x4*)in)[i];
  us4 o;
  o[0] = f2bf(v[0]); o[1] = f2bf(v[1]); o[2] = f2bf(v[2]); o[3] = f2bf(v[3]);
  ((us4*)out)[i] = o;
}

// x_proj_w (160 x 4096) -> bf16 padded to (256 x 4096), pad rows zero
__global__ __launch_bounds__(256) void cvt_xw(const float* __restrict__ in,
                                              u16* __restrict__ out) {
  int i = blockIdx.x * 256 + threadIdx.x;  // 262144 total (256*4096/4)
  int row = (i << 2) >> 12;
  us4 o;
  if (row < 160) {
    f32x4 v = ((const f32x4*)in)[i];
    o[0] = f2bf(v[0]); o[1] = f2bf(v[1]); o[2] = f2bf(v[2]); o[3] = f2bf(v[3]);
  } else {
    o[0] = 0; o[1] = 0; o[2] = 0; o[3] = 0;
  }
  ((us4*)out)[i] = o;
}

// dt_r: first 128 cols of ssm_p (4096 x 256 fp32) -> bf16 (4096 x 128)
__global__ __launch_bounds__(256) void cvt_dtr(const float* __restrict__ smp,
                                               u16* __restrict__ out) {
  int i = blockIdx.x * 256 + threadIdx.x;  // 131072 total
  int e = i << 2;
  int t = e >> 7, r = e & 127;
  f32x4 v = *(const f32x4*)(smp + t * 256 + r);
  us4 o;
  o[0] = f2bf(v[0]); o[1] = f2bf(v[1]); o[2] = f2bf(v[2]); o[3] = f2bf(v[3]);
  ((us4*)out)[i] = o;
}

// depthwise causal conv (K=4) + bias + SiLU.  U: (4096 tok x 4096) bf16
// (u_raw), out: bf16 same layout.  4 channels per thread.
__global__ __launch_bounds__(256) void conv_silu(const u16* __restrict__ U,
                                                 const float* __restrict__ cw,
                                                 const float* __restrict__ cb,
                                                 u16* __restrict__ out) {
  int i = blockIdx.x * 256 + threadIdx.x;  // 4096 * 1024
  int t = i >> 10;
  int d4 = (i & 1023) << 2;
  int l = t & 2047;
  float w[4][4];
#pragma unroll
  for (int j = 0; j < 4; ++j) {
    f32x4 wv = *(const f32x4*)(cw + (d4 + j) * 4);
    w[j][0] = wv[0]; w[j][1] = wv[1]; w[j][2] = wv[2]; w[j][3] = wv[3];
  }
  float r[4] = {cb[d4], cb[d4 + 1], cb[d4 + 2], cb[d4 + 3]};
#pragma unroll
  for (int k = 0; k < 4; ++k) {
    int ll = l - 3 + k;
    if (ll >= 0) {
      us4 xv = *(const us4*)(U + (size_t)(t - 3 + k) * 4096 + d4);
      r[0] += w[0][k] * bf2f(xv[0]);
      r[1] += w[1][k] * bf2f(xv[1]);
      r[2] += w[2][k] * bf2f(xv[2]);
      r[3] += w[3][k] * bf2f(xv[3]);
    }
  }
  us4 o;
#pragma unroll
  for (int j = 0; j < 4; ++j) {
    float v = r[j];
    float s = v / (1.f + __expf(-v));
    o[j] = f2bf(s);
  }
  *(us4*)(out + (size_t)t * 4096 + d4) = o;
}

// selective scan: thread = (b, d, n); 16-lane groups reduce over n.
// Writes yb = (y_scan + u*D) * silu(gate) as bf16 (GEMM A operand).
__global__ __launch_bounds__(256) void ssm_scan(
    const float* __restrict__ dtraw, const float* __restrict__ dtb,
    const float* __restrict__ ssmp, const u16* __restrict__ ub,
    const u16* __restrict__ gb, const float* __restrict__ Alog,
    const float* __restrict__ Dv, u16* __restrict__ yb) {
  const int tid = threadIdx.x;
  const int n = tid & 15;
  const int grp = tid >> 4;
  const int blk = blockIdx.x;  // 512 blocks: 256 per batch
  const int b = blk >> 8;
  const int d = ((blk & 255) << 4) + grp;
  const float A = -__expf(Alog[d * 16 + n]);
  const float Dd = Dv[d];
  const float bias = dtb[d];
  const int base = b * 2048;

  const float* dtp = dtraw + (size_t)base * 4096 + d;
  const u16* up = ub + (size_t)base * 4096 + d;
  const u16* gp = gb + (size_t)base * 4096 + d;
  const float* Bp = ssmp + (size_t)base * 256 + 128 + n;
  u16* yo = yb + (size_t)base * 4096 + d;

  float cdt[8], cu[8], cB[8], cC[8], cg[8];
  float ndt[8] = {}, nu[8] = {}, nB[8] = {}, nC[8] = {}, ng[8] = {};
#pragma unroll
  for (int j = 0; j < 8; ++j) {
    cdt[j] = dtp[j * 4096];
    cu[j] = bf2f(up[j * 4096]);
    cB[j] = Bp[j * 256];
    cC[j] = Bp[j * 256 + 16];
    cg[j] = bf2f(gp[j * 4096]);
  }
  float s = 0.f;
  for (int l0 = 0; l0 < 2048; l0 += 8) {
    if (l0 + 8 < 2048) {
      int o = (l0 + 8) * 4096;
      int o2 = (l0 + 8) * 256;
#pragma unroll
      for (int j = 0; j < 8; ++j) {
        ndt[j] = dtp[o + j * 4096];
        nu[j] = bf2f(up[o + j * 4096]);
        nB[j] = Bp[o2 + j * 256];
        nC[j] = Bp[o2 + j * 256 + 16];
        ng[j] = bf2f(gp[o + j * 4096]);
      }
    }
#pragma unroll
    for (int j = 0; j < 8; ++j) {
      float dtv = cdt[j] + bias;
      float dt = (dtv > 20.f) ? dtv : log1pf(__expf(dtv));
      s = __expf(dt * A) * s + (dt * cu[j]) * cB[j];
      float yv = s * cC[j];
      yv += __shfl_xor(yv, 1);
      yv += __shfl_xor(yv, 2);
      yv += __shfl_xor(yv, 4);
      yv += __shfl_xor(yv, 8);
      if (n == 0) {
        float gv = cg[j];
        float sig = 1.f / (1.f + __expf(-gv));
        yo[(l0 + j) * 4096] = f2bf((yv + cu[j] * Dd) * (gv * sig));
      }
    }
#pragma unroll
    for (int j = 0; j < 8; ++j) {
      cdt[j] = ndt[j]; cu[j] = nu[j]; cB[j] = nB[j]; cC[j] = nC[j]; cg[j] = ng[j];
    }
  }
}

extern "C" void kernel_launch(void* const* d_in, const int* in_sizes, int n_in,
                              void* d_out, int out_size, void* d_ws,
                              size_t ws_size, hipStream_t stream) {
  (void)in_sizes; (void)n_in; (void)out_size; (void)ws_size;
  const float* hs = (const float*)d_in[0];    // (2,2048,2048)
  const float* wIn = (const float*)d_in[1];   // (8192,2048)
  const float* cw = (const float*)d_in[2];    // (4096,1,4)
  const float* cb = (const float*)d_in[3];    // (4096)
  const float* wX = (const float*)d_in[4];    // (160,4096)
  const float* wDt = (const float*)d_in[5];   // (4096,128)
  const float* bDt = (const float*)d_in[6];   // (4096)
  const float* Alog = (const float*)d_in[7];  // (4096,16)
  const float* Dv = (const float*)d_in[8];    // (4096)
  const float* wOut = (const float*)d_in[9];  // (2048,4096)

  // ---- workspace layout (byte offsets, peak 152 MB) -----------------------
  // [0,16M)    Xb   (bf16 hs)          dead after in_proj
  // [16M,48M)  Winb (bf16 in_proj_w)   dead after in_proj
  // [48M,80M)  Pu   (u_raw)            dead after conv
  // [0,64M)    DtF32 (dt_proj out)     written step 6 (over Xb/Winb/Pu head)
  // [64M,96M)  Yb                      written step 7 (over Pu tail + fresh)
  // [96M,128M) Ub   (conv+silu out)
  // [128M,130M) Wxb  (padded x_proj_w)
  // [130M,134M) Smp  (x_proj out fp32)
  // [134M,135M) Dtrb (dt_r bf16)
  // [135M,136M) Wdtb (dt_proj_w bf16)
  // [136M,152M) Wob  (out_proj_w bf16)
  // Pg (gate bf16, 32MB) lives in d_out (fp32 out only written in step 8).
  const size_t MB = 1ull << 20;
  char* w = (char*)d_ws;
  u16* Xb = (u16*)(w + 0 * MB);
  u16* Winb = (u16*)(w + 16 * MB);
  u16* Pu = (u16*)(w + 48 * MB);
  float* DtF = (float*)(w + 0 * MB);
  u16* Yb = (u16*)(w + 64 * MB);
  u16* Ub = (u16*)(w + 96 * MB);
  u16* Wxb = (u16*)(w + 128 * MB);
  float* Smp = (float*)(w + 130 * MB);
  u16* Dtrb = (u16*)(w + 134 * MB);
  u16* Wdtb = (u16*)(w + 135 * MB);
  u16* Wob = (u16*)(w + 136 * MB);
  u16* Pg = (u16*)d_out;

  // step 1: weight / input converts
  cvt_bf16<<<8192, 256, 0, stream>>>(hs, Xb, 2097152);
  cvt_bf16<<<16384, 256, 0, stream>>>(wIn, Winb, 4194304);
  cvt_xw<<<1024, 256, 0, stream>>>(wX, Wxb);
  cvt_bf16<<<512, 256, 0, stream>>>(wDt, Wdtb, 131072);
  cvt_bf16<<<8192, 256, 0, stream>>>(wOut, Wob, 2097152);

  // step 2: in_proj (u half and gate half)
  gemm_bt<true><<<dim3(32, 32), 256, 0, stream>>>(Xb, Winb, Pu, 2048, 4096);
  gemm_bt<true><<<dim3(32, 32), 256, 0, stream>>>(Xb, Winb + 4096L * 2048, Pg, 2048, 4096);
  // step 3: depthwise conv + silu
  conv_silu<<<16384, 256, 0, stream>>>(Pu, cw, cb, Ub);
  // step 4: x_proj (N padded 160 -> 256)
  gemm_bt<false><<<dim3(2, 32), 256, 0, stream>>>(Ub, Wxb, Smp, 4096, 256);
  // step 5: extract dt_r as bf16
  cvt_dtr<<<512, 256, 0, stream>>>(Smp, Dtrb);
  // step 6: dt_proj (fp32 out, over dead Xb/Winb/Pu-head region)
  gemm_bt<false><<<dim3(32, 32), 256, 0, stream>>>(Dtrb, Wdtb, DtF, 128, 4096);
  // step 7: selective scan + gating -> bf16 Y
  ssm_scan<<<512, 256, 0, stream>>>(DtF, bDt, Smp, Ub, Pg, Alog, Dv, Yb);
  // step 8: out_proj -> fp32 output (overwrites Pg/d_out entirely)
  gemm_bt<false><<<dim3(16, 32), 256, 0, stream>>>(Yb, Wob, (float*)d_out, 4096, 2048);
}

// Round 5
// 1159.278 us; speedup vs baseline: 1.7351x; 1.7351x over previous
//
#include <hip/hip_runtime.h>

typedef unsigned int u32;
typedef unsigned short u16;
typedef float f32x4 __attribute__((ext_vector_type(4)));
typedef u16 us4 __attribute__((ext_vector_type(4)));
typedef u16 us8 __attribute__((ext_vector_type(8)));
typedef __bf16 bf16x8 __attribute__((ext_vector_type(8)));

__device__ __forceinline__ u16 f2bf(float f) {
  u32 u = __builtin_bit_cast(u32, f);
  u += 0x7fffu + ((u >> 16) & 1u);
  return (u16)(u >> 16);
}
__device__ __forceinline__ float bf2f(u16 h) {
  u32 u = ((u32)h) << 16;
  return __builtin_bit_cast(float, u);
}
__device__ __forceinline__ void async16(const void* g, void* l) {
  __builtin_amdgcn_global_load_lds((const __attribute__((address_space(1))) void*)g,
                                   (__attribute__((address_space(3))) void*)l, 16, 0, 0);
}

// ---------------------------------------------------------------------------
// C = A * B^T.  A: M x K bf16 row-major. B: N x K bf16 row-major. C: M x N
// (row stride ldc).  ACT: 0 = fp32 store, 1 = bf16 store, 2 = bf16 silu,
// 3 = fp32 softplus(acc + bias[col]).
// ---------------------------------------------------------------------------
template <int ACT>
__global__ __launch_bounds__(256) void gemm_bt(const u16* __restrict__ A,
                                               const u16* __restrict__ B,
                                               void* __restrict__ Cv,
                                               const float* __restrict__ bias,
                                               int K, int ldc) {
  __shared__ __align__(16) u16 As[128 * 32];
  __shared__ __align__(16) u16 Bs[128 * 32];
  const int tid = threadIdx.x;
  const int lane = tid & 63;
  const int wave = tid >> 6;
  const int lm = lane & 15;
  const int quad = lane >> 4;
  const int wm = (wave >> 1) << 6;  // wave M offset (0/64)
  const int wn = (wave & 1) << 6;   // wave N offset (0/64)
  const long rowBase = (long)blockIdx.y << 7;
  const long colBase = (long)blockIdx.x << 7;

  const int r0 = tid >> 2;
  const int cc0 = (tid & 3) << 3;
  const u16* Ag0 = A + (rowBase + r0) * (long)K + cc0;
  const u16* Ag1 = Ag0 + 64L * K;
  const u16* Bg0 = B + (colBase + r0) * (long)K + cc0;
  const u16* Bg1 = Bg0 + 64L * K;
  u16* Al0 = As + tid * 8;
  u16* Al1 = As + (tid + 256) * 8;
  u16* Bl0 = Bs + tid * 8;
  u16* Bl1 = Bs + (tid + 256) * 8;

  f32x4 acc[4][4] = {};

  for (int k0 = 0; k0 < K; k0 += 32) {
    async16(Ag0 + k0, Al0);
    async16(Ag1 + k0, Al1);
    async16(Bg0 + k0, Bl0);
    async16(Bg1 + k0, Bl1);
    __syncthreads();
    us8 af[4], bfr[4];
#pragma unroll
    for (int i = 0; i < 4; ++i)
      af[i] = *(const us8*)(As + (wm + i * 16 + lm) * 32 + quad * 8);
#pragma unroll
    for (int i = 0; i < 4; ++i)
      bfr[i] = *(const us8*)(Bs + (wn + i * 16 + lm) * 32 + quad * 8);
#pragma unroll
    for (int i = 0; i < 4; ++i)
#pragma unroll
      for (int j = 0; j < 4; ++j)
        acc[i][j] = __builtin_amdgcn_mfma_f32_16x16x32_bf16(
            __builtin_bit_cast(bf16x8, af[i]), __builtin_bit_cast(bf16x8, bfr[j]),
            acc[i][j], 0, 0, 0);
    __syncthreads();
  }

#pragma unroll
  for (int i = 0; i < 4; ++i)
#pragma unroll
    for (int j = 0; j < 4; ++j)
#pragma unroll
      for (int r = 0; r < 4; ++r) {
        long row = rowBase + wm + i * 16 + quad * 4 + r;
        long col = colBase + wn + j * 16 + lm;
        float v = acc[i][j][r];
        if constexpr (ACT == 0) {
          ((float*)Cv)[row * ldc + col] = v;
        } else if constexpr (ACT == 1) {
          ((u16*)Cv)[row * ldc + col] = f2bf(v);
        } else if constexpr (ACT == 2) {
          float s = v / (1.f + __expf(-v));
          ((u16*)Cv)[row * ldc + col] = f2bf(s);
        } else {
          v += bias[col];
          float sp = (v > 20.f) ? v : log1pf(__expf(v));
          ((float*)Cv)[row * ldc + col] = sp;
        }
      }
}

// fp32 -> bf16, 4 elems/thread
__global__ __launch_bounds__(256) void cvt_bf16(const float* __restrict__ in,
                                                u16* __restrict__ out, int n4) {
  int i = blockIdx.x * 256 + threadIdx.x;
  if (i >= n4) return;
  f32x4 v = ((const f32x4*)in)[i];
  us4 o;
  o[0] = f2bf(v[0]); o[1] = f2bf(v[1]); o[2] = f2bf(v[2]); o[3] = f2bf(v[3]);
  ((us4*)out)[i] = o;
}

// x_proj_w (160 x 4096) -> bf16 padded to (256 x 4096), pad rows zero
__global__ __launch_bounds__(256) void cvt_xw(const float* __restrict__ in,
                                              u16* __restrict__ out) {
  int i = blockIdx.x * 256 + threadIdx.x;
  int row = (i << 2) >> 12;
  us4 o;
  if (row < 160) {
    f32x4 v = ((const f32x4*)in)[i];
    o[0] = f2bf(v[0]); o[1] = f2bf(v[1]); o[2] = f2bf(v[2]); o[3] = f2bf(v[3]);
  } else {
    o[0] = 0; o[1] = 0; o[2] = 0; o[3] = 0;
  }
  ((us4*)out)[i] = o;
}

// dt_r: first 128 cols of ssm_p (4096 x 256 fp32) -> bf16 (4096 x 128)
__global__ __launch_bounds__(256) void cvt_dtr(const float* __restrict__ smp,
                                               u16* __restrict__ out) {
  int i = blockIdx.x * 256 + threadIdx.x;
  int e = i << 2;
  int t = e >> 7, r = e & 127;
  f32x4 v = *(const f32x4*)(smp + t * 256 + r);
  us4 o;
  o[0] = f2bf(v[0]); o[1] = f2bf(v[1]); o[2] = f2bf(v[2]); o[3] = f2bf(v[3]);
  ((us4*)out)[i] = o;
}

// depthwise causal conv (K=4) + bias + SiLU
__global__ __launch_bounds__(256) void conv_silu(const u16* __restrict__ U,
                                                 const float* __restrict__ cw,
                                                 const float* __restrict__ cb,
                                                 u16* __restrict__ out) {
  int i = blockIdx.x * 256 + threadIdx.x;
  int t = i >> 10;
  int d4 = (i & 1023) << 2;
  int l = t & 2047;
  float w[4][4];
#pragma unroll
  for (int j = 0; j < 4; ++j) {
    f32x4 wv = *(const f32x4*)(cw + (d4 + j) * 4);
    w[j][0] = wv[0]; w[j][1] = wv[1]; w[j][2] = wv[2]; w[j][3] = wv[3];
  }
  float r[4] = {cb[d4], cb[d4 + 1], cb[d4 + 2], cb[d4 + 3]};
#pragma unroll
  for (int k = 0; k < 4; ++k) {
    int ll = l - 3 + k;
    if (ll >= 0) {
      us4 xv = *(const us4*)(U + (size_t)(t - 3 + k) * 4096 + d4);
      r[0] += w[0][k] * bf2f(xv[0]);
      r[1] += w[1][k] * bf2f(xv[1]);
      r[2] += w[2][k] * bf2f(xv[2]);
      r[3] += w[3][k] * bf2f(xv[3]);
    }
  }
  us4 o;
#pragma unroll
  for (int j = 0; j < 4; ++j) {
    float v = r[j];
    float s = v / (1.f + __expf(-v));
    o[j] = f2bf(s);
  }
  *(us4*)(out + (size_t)t * 4096 + d4) = o;
}

// ---------------------------------------------------------------------------
// Chunked selective scan.  L=2048 split into 16 chunks of 128.
// thread = (b, d, n):  n = tid&15, d = blockIdx.y*16 + (tid>>4), b=blockIdx.z,
// chunk = blockIdx.x.  dt is ALREADY softplus'd (fused in dt_proj GEMM).
// ---------------------------------------------------------------------------
// Pass 1: per-chunk transition summary (P = prod dA, S = state from 0).
__global__ __launch_bounds__(256) void scan_part(
    const float* __restrict__ dt, const u16* __restrict__ ub,
    const float* __restrict__ ssmp, const float* __restrict__ Alog,
    float* __restrict__ Pout, float* __restrict__ Sout) {
  const int tid = threadIdx.x;
  const int n = tid & 15, grp = tid >> 4;
  const int chunk = blockIdx.x, dblk = blockIdx.y, b = blockIdx.z;
  const int d = dblk * 16 + grp;
  const float A = -__expf(Alog[d * 16 + n]);
  const int base = b * 2048 + chunk * 128;
  const float* dtp = dt + (size_t)base * 4096 + d;
  const u16* up = ub + (size_t)base * 4096 + d;
  const float* Bp = ssmp + (size_t)base * 256 + 128 + n;

  float cdt[8], cu[8], cB[8];
  float ndt[8] = {}, nu[8] = {}, nB[8] = {};
#pragma unroll
  for (int j = 0; j < 8; ++j) {
    cdt[j] = dtp[j * 4096];
    cu[j] = bf2f(up[j * 4096]);
    cB[j] = Bp[j * 256];
  }
  float P = 1.f, S = 0.f;
  for (int l0 = 0; l0 < 128; l0 += 8) {
    if (l0 + 8 < 128) {
      int o = (l0 + 8) * 4096, o2 = (l0 + 8) * 256;
#pragma unroll
      for (int j = 0; j < 8; ++j) {
        ndt[j] = dtp[o + j * 4096];
        nu[j] = bf2f(up[o + j * 4096]);
        nB[j] = Bp[o2 + j * 256];
      }
    }
#pragma unroll
    for (int j = 0; j < 8; ++j) {
      float e = __expf(cdt[j] * A);
      P *= e;
      S = e * S + (cdt[j] * cu[j]) * cB[j];
    }
#pragma unroll
    for (int j = 0; j < 8; ++j) { cdt[j] = ndt[j]; cu[j] = nu[j]; cB[j] = nB[j]; }
  }
  size_t idx = ((size_t)(b * 4096 + d) * 16 + n) * 16 + chunk;
  Pout[idx] = P;
  Sout[idx] = S;
}

// Pass 2: fold chunk summaries into init state, replay chunk producing y.
// gs = silu(gate) bf16 (fused in in_proj gate GEMM).
__global__ __launch_bounds__(256) void scan_y(
    const float* __restrict__ dt, const u16* __restrict__ ub,
    const float* __restrict__ ssmp, const u16* __restrict__ gs,
    const float* __restrict__ Alog, const float* __restrict__ Dv,
    const float* __restrict__ Pin, const float* __restrict__ Sin,
    u16* __restrict__ yb) {
  const int tid = threadIdx.x;
  const int n = tid & 15, grp = tid >> 4;
  const int chunk = blockIdx.x, dblk = blockIdx.y, b = blockIdx.z;
  const int d = dblk * 16 + grp;
  const float A = -__expf(Alog[d * 16 + n]);
  const float Dd = Dv[d];
  const int base = b * 2048 + chunk * 128;
  const float* dtp = dt + (size_t)base * 4096 + d;
  const u16* up = ub + (size_t)base * 4096 + d;
  const u16* gp = gs + (size_t)base * 4096 + d;
  const float* Bp = ssmp + (size_t)base * 256 + 128 + n;
  u16* yo = yb + (size_t)base * 4096 + d;

  // fold prior chunks' summaries into initial state
  float s = 0.f;
  {
    size_t idx = ((size_t)(b * 4096 + d) * 16 + n) * 16;
    for (int k = 0; k < chunk; ++k) s = Pin[idx + k] * s + Sin[idx + k];
  }

  float cdt[8], cu[8], cB[8], cC[8], cg[8];
  float ndt[8] = {}, nu[8] = {}, nB[8] = {}, nC[8] = {}, ng[8] = {};
#pragma unroll
  for (int j = 0; j < 8; ++j) {
    cdt[j] = dtp[j * 4096];
    cu[j] = bf2f(up[j * 4096]);
    cB[j] = Bp[j * 256];
    cC[j] = Bp[j * 256 + 16];
    cg[j] = bf2f(gp[j * 4096]);
  }
  for (int l0 = 0; l0 < 128; l0 += 8) {
    if (l0 + 8 < 128) {
      int o = (l0 + 8) * 4096, o2 = (l0 + 8) * 256;
#pragma unroll
      for (int j = 0; j < 8; ++j) {
        ndt[j] = dtp[o + j * 4096];
        nu[j] = bf2f(up[o + j * 4096]);
        nB[j] = Bp[o2 + j * 256];
        nC[j] = Bp[o2 + j * 256 + 16];
        ng[j] = bf2f(gp[o + j * 4096]);
      }
    }
#pragma unroll
    for (int j = 0; j < 8; ++j) {
      float e = __expf(cdt[j] * A);
      s = e * s + (cdt[j] * cu[j]) * cB[j];
      float yv = s * cC[j];
      yv += __shfl_xor(yv, 1);
      yv += __shfl_xor(yv, 2);
      yv += __shfl_xor(yv, 4);
      yv += __shfl_xor(yv, 8);
      if (n == 0) {
        yo[(l0 + j) * 4096] = f2bf((yv + cu[j] * Dd) * cg[j]);
      }
    }
#pragma unroll
    for (int j = 0; j < 8; ++j) {
      cdt[j] = ndt[j]; cu[j] = nu[j]; cB[j] = nB[j]; cC[j] = nC[j]; cg[j] = ng[j];
    }
  }
}

extern "C" void kernel_launch(void* const* d_in, const int* in_sizes, int n_in,
                              void* d_out, int out_size, void* d_ws,
                              size_t ws_size, hipStream_t stream) {
  (void)in_sizes; (void)n_in; (void)out_size; (void)ws_size;
  const float* hs = (const float*)d_in[0];    // (2,2048,2048)
  const float* wIn = (const float*)d_in[1];   // (8192,2048)
  const float* cw = (const float*)d_in[2];    // (4096,1,4)
  const float* cb = (const float*)d_in[3];    // (4096)
  const float* wX = (const float*)d_in[4];    // (160,4096)
  const float* wDt = (const float*)d_in[5];   // (4096,128)
  const float* bDt = (const float*)d_in[6];   // (4096)
  const float* Alog = (const float*)d_in[7];  // (4096,16)
  const float* Dv = (const float*)d_in[8];    // (4096)
  const float* wOut = (const float*)d_in[9];  // (2048,4096)

  // ---- workspace layout (byte offsets, peak 168 MB) -----------------------
  // [0,16M)    Xb   (bf16 hs)          dead after in_proj
  // [16M,48M)  Winb (bf16 in_proj_w)   dead after in_proj
  // [48M,80M)  Pu   (u_raw)            dead after conv
  // [0,64M)    DtF32 (softplus dt)     written step 6 (over Xb/Winb/Pu head)
  // [64M,96M)  Yb                      written pass-2 (over Pu tail + fresh)
  // [96M,128M) Ub   (conv+silu out)
  // [128M,130M) Wxb  (padded x_proj_w)
  // [130M,134M) Smp  (x_proj out fp32)
  // [134M,135M) Dtrb (dt_r bf16)
  // [135M,136M) Wdtb (dt_proj_w bf16)
  // [136M,152M) Wob  (out_proj_w bf16)
  // [152M,160M) Pchk (chunk products)
  // [160M,168M) Schk (chunk states)
  // Pg (silu(gate) bf16, 32MB) lives in d_out (only overwritten in step 8).
  const size_t MB = 1ull << 20;
  char* w = (char*)d_ws;
  u16* Xb = (u16*)(w + 0 * MB);
  u16* Winb = (u16*)(w + 16 * MB);
  u16* Pu = (u16*)(w + 48 * MB);
  float* DtF = (float*)(w + 0 * MB);
  u16* Yb = (u16*)(w + 64 * MB);
  u16* Ub = (u16*)(w + 96 * MB);
  u16* Wxb = (u16*)(w + 128 * MB);
  float* Smp = (float*)(w + 130 * MB);
  u16* Dtrb = (u16*)(w + 134 * MB);
  u16* Wdtb = (u16*)(w + 135 * MB);
  u16* Wob = (u16*)(w + 136 * MB);
  float* Pchk = (float*)(w + 152 * MB);
  float* Schk = (float*)(w + 160 * MB);
  u16* Pg = (u16*)d_out;

  // step 1: weight / input converts
  cvt_bf16<<<8192, 256, 0, stream>>>(hs, Xb, 2097152);
  cvt_bf16<<<16384, 256, 0, stream>>>(wIn, Winb, 4194304);
  cvt_xw<<<1024, 256, 0, stream>>>(wX, Wxb);
  cvt_bf16<<<512, 256, 0, stream>>>(wDt, Wdtb, 131072);
  cvt_bf16<<<8192, 256, 0, stream>>>(wOut, Wob, 2097152);

  // step 2: in_proj (u half plain bf16; gate half fused silu)
  gemm_bt<1><<<dim3(32, 32), 256, 0, stream>>>(Xb, Winb, Pu, nullptr, 2048, 4096);
  gemm_bt<2><<<dim3(32, 32), 256, 0, stream>>>(Xb, Winb + 4096L * 2048, Pg, nullptr, 2048, 4096);
  // step 3: depthwise conv + silu
  conv_silu<<<16384, 256, 0, stream>>>(Pu, cw, cb, Ub);
  // step 4: x_proj (N padded 160 -> 256)
  gemm_bt<0><<<dim3(2, 32), 256, 0, stream>>>(Ub, Wxb, Smp, nullptr, 4096, 256);
  // step 5: extract dt_r as bf16
  cvt_dtr<<<512, 256, 0, stream>>>(Smp, Dtrb);
  // step 6: dt_proj with fused softplus(acc + bias) -> fp32 dt
  gemm_bt<3><<<dim3(32, 32), 256, 0, stream>>>(Dtrb, Wdtb, DtF, bDt, 128, 4096);
  // step 7: chunked selective scan (pass 1: summaries, pass 2: y)
  scan_part<<<dim3(16, 256, 2), 256, 0, stream>>>(DtF, Ub, Smp, Alog, Pchk, Schk);
  scan_y<<<dim3(16, 256, 2), 256, 0, stream>>>(DtF, Ub, Smp, Pg, Alog, Dv, Pchk, Schk, Yb);
  // step 8: out_proj -> fp32 output (overwrites Pg/d_out entirely)
  gemm_bt<0><<<dim3(16, 32), 256, 0, stream>>>(Yb, Wob, (float*)d_out, nullptr, 4096, 2048);
}

// Round 6
// 811.680 us; speedup vs baseline: 2.4781x; 1.4282x over previous
//
#include <hip/hip_runtime.h>

typedef unsigned int u32;
typedef unsigned short u16;
typedef float f32x4 __attribute__((ext_vector_type(4)));
typedef u16 us4 __attribute__((ext_vector_type(4)));
typedef u16 us8 __attribute__((ext_vector_type(8)));
typedef __bf16 bf16x8 __attribute__((ext_vector_type(8)));

__device__ __forceinline__ u16 f2bf(float f) {
  u32 u = __builtin_bit_cast(u32, f);
  u += 0x7fffu + ((u >> 16) & 1u);
  return (u16)(u >> 16);
}
__device__ __forceinline__ float bf2f(u16 h) {
  u32 u = ((u32)h) << 16;
  return __builtin_bit_cast(float, u);
}
__device__ __forceinline__ void async16(const void* g, void* l) {
  __builtin_amdgcn_global_load_lds((const __attribute__((address_space(1))) void*)g,
                                   (__attribute__((address_space(3))) void*)l, 16, 0, 0);
}

// ---------------------------------------------------------------------------
// C = A * B^T.  A: M x K bf16 row-major. B: N x K bf16 row-major. C: M x N
// (row stride ldc).  ACT: 0 = fp32 store, 1 = bf16 store, 2 = bf16 silu,
// 3 = fp32 softplus(acc + bias[col]).
// ---------------------------------------------------------------------------
template <int ACT>
__global__ __launch_bounds__(256) void gemm_bt(const u16* __restrict__ A,
                                               const u16* __restrict__ B,
                                               void* __restrict__ Cv,
                                               const float* __restrict__ bias,
                                               int K, int ldc) {
  __shared__ __align__(16) u16 As[128 * 32];
  __shared__ __align__(16) u16 Bs[128 * 32];
  const int tid = threadIdx.x;
  const int lane = tid & 63;
  const int wave = tid >> 6;
  const int lm = lane & 15;
  const int quad = lane >> 4;
  const int wm = (wave >> 1) << 6;  // wave M offset (0/64)
  const int wn = (wave & 1) << 6;   // wave N offset (0/64)
  const long rowBase = (long)blockIdx.y << 7;
  const long colBase = (long)blockIdx.x << 7;

  const int r0 = tid >> 2;
  const int cc0 = (tid & 3) << 3;
  const u16* Ag0 = A + (rowBase + r0) * (long)K + cc0;
  const u16* Ag1 = Ag0 + 64L * K;
  const u16* Bg0 = B + (colBase + r0) * (long)K + cc0;
  const u16* Bg1 = Bg0 + 64L * K;
  u16* Al0 = As + tid * 8;
  u16* Al1 = As + (tid + 256) * 8;
  u16* Bl0 = Bs + tid * 8;
  u16* Bl1 = Bs + (tid + 256) * 8;

  f32x4 acc[4][4] = {};

  for (int k0 = 0; k0 < K; k0 += 32) {
    async16(Ag0 + k0, Al0);
    async16(Ag1 + k0, Al1);
    async16(Bg0 + k0, Bl0);
    async16(Bg1 + k0, Bl1);
    __syncthreads();
    us8 af[4], bfr[4];
#pragma unroll
    for (int i = 0; i < 4; ++i)
      af[i] = *(const us8*)(As + (wm + i * 16 + lm) * 32 + quad * 8);
#pragma unroll
    for (int i = 0; i < 4; ++i)
      bfr[i] = *(const us8*)(Bs + (wn + i * 16 + lm) * 32 + quad * 8);
#pragma unroll
    for (int i = 0; i < 4; ++i)
#pragma unroll
      for (int j = 0; j < 4; ++j)
        acc[i][j] = __builtin_amdgcn_mfma_f32_16x16x32_bf16(
            __builtin_bit_cast(bf16x8, af[i]), __builtin_bit_cast(bf16x8, bfr[j]),
            acc[i][j], 0, 0, 0);
    __syncthreads();
  }

#pragma unroll
  for (int i = 0; i < 4; ++i)
#pragma unroll
    for (int j = 0; j < 4; ++j)
#pragma unroll
      for (int r = 0; r < 4; ++r) {
        long row = rowBase + wm + i * 16 + quad * 4 + r;
        long col = colBase + wn + j * 16 + lm;
        float v = acc[i][j][r];
        if constexpr (ACT == 0) {
          ((float*)Cv)[row * ldc + col] = v;
        } else if constexpr (ACT == 1) {
          ((u16*)Cv)[row * ldc + col] = f2bf(v);
        } else if constexpr (ACT == 2) {
          float s = v / (1.f + __expf(-v));
          ((u16*)Cv)[row * ldc + col] = f2bf(s);
        } else {
          v += bias[col];
          float sp = (v > 20.f) ? v : log1pf(__expf(v));
          ((float*)Cv)[row * ldc + col] = sp;
        }
      }
}

// fp32 -> bf16, 4 elems/thread
__global__ __launch_bounds__(256) void cvt_bf16(const float* __restrict__ in,
                                                u16* __restrict__ out, int n4) {
  int i = blockIdx.x * 256 + threadIdx.x;
  if (i >= n4) return;
  f32x4 v = ((const f32x4*)in)[i];
  us4 o;
  o[0] = f2bf(v[0]); o[1] = f2bf(v[1]); o[2] = f2bf(v[2]); o[3] = f2bf(v[3]);
  ((us4*)out)[i] = o;
}

// x_proj_w (160 x 4096) -> bf16 padded to (256 x 4096), pad rows zero
__global__ __launch_bounds__(256) void cvt_xw(const float* __restrict__ in,
                                              u16* __restrict__ out) {
  int i = blockIdx.x * 256 + threadIdx.x;
  int row = (i << 2) >> 12;
  us4 o;
  if (row < 160) {
    f32x4 v = ((const f32x4*)in)[i];
    o[0] = f2bf(v[0]); o[1] = f2bf(v[1]); o[2] = f2bf(v[2]); o[3] = f2bf(v[3]);
  } else {
    o[0] = 0; o[1] = 0; o[2] = 0; o[3] = 0;
  }
  ((us4*)out)[i] = o;
}

// dt_r: first 128 cols of ssm_p (4096 x 256 fp32) -> bf16 (4096 x 128)
__global__ __launch_bounds__(256) void cvt_dtr(const float* __restrict__ smp,
                                               u16* __restrict__ out) {
  int i = blockIdx.x * 256 + threadIdx.x;
  int e = i << 2;
  int t = e >> 7, r = e & 127;
  f32x4 v = *(const f32x4*)(smp + t * 256 + r);
  us4 o;
  o[0] = f2bf(v[0]); o[1] = f2bf(v[1]); o[2] = f2bf(v[2]); o[3] = f2bf(v[3]);
  ((us4*)out)[i] = o;
}

// depthwise causal conv (K=4) + bias + SiLU
__global__ __launch_bounds__(256) void conv_silu(const u16* __restrict__ U,
                                                 const float* __restrict__ cw,
                                                 const float* __restrict__ cb,
                                                 u16* __restrict__ out) {
  int i = blockIdx.x * 256 + threadIdx.x;
  int t = i >> 10;
  int d4 = (i & 1023) << 2;
  int l = t & 2047;
  float w[4][4];
#pragma unroll
  for (int j = 0; j < 4; ++j) {
    f32x4 wv = *(const f32x4*)(cw + (d4 + j) * 4);
    w[j][0] = wv[0]; w[j][1] = wv[1]; w[j][2] = wv[2]; w[j][3] = wv[3];
  }
  float r[4] = {cb[d4], cb[d4 + 1], cb[d4 + 2], cb[d4 + 3]};
#pragma unroll
  for (int k = 0; k < 4; ++k) {
    int ll = l - 3 + k;
    if (ll >= 0) {
      us4 xv = *(const us4*)(U + (size_t)(t - 3 + k) * 4096 + d4);
      r[0] += w[0][k] * bf2f(xv[0]);
      r[1] += w[1][k] * bf2f(xv[1]);
      r[2] += w[2][k] * bf2f(xv[2]);
      r[3] += w[3][k] * bf2f(xv[3]);
    }
  }
  us4 o;
#pragma unroll
  for (int j = 0; j < 4; ++j) {
    float v = r[j];
    float s = v / (1.f + __expf(-v));
    o[j] = f2bf(s);
  }
  *(us4*)(out + (size_t)t * 4096 + d4) = o;
}

// ---------------------------------------------------------------------------
// Chunked selective scan, channel-per-thread layout.
// thread = (b, d): holds all 16 n-states in VGPRs.  d = blockIdx.y*256 + tid
// (coalesced dt/u/g loads + y store), chunk = blockIdx.x (16 x 128 steps),
// b = blockIdx.z.  B/C reads are wave-uniform (scalarizable).
// Fast path exploits A[n] = (n+1)*A[0] (A_log = log(1..16) broadcast):
// e[n] = e1^(n+1), 1 exp + 15 muls per step; wave-uniform ballot guard with
// generic 16-exp fallback.
// P summary = exp(dtsum*A[n]) -- only dtsum accumulated per step in pass 1.
// ---------------------------------------------------------------------------
__global__ __launch_bounds__(256) void scan_part(
    const float* __restrict__ dt, const u16* __restrict__ ub,
    const float* __restrict__ ssmp, const float* __restrict__ Alog,
    float* __restrict__ Pout, float* __restrict__ Sout) {
  const int tid = threadIdx.x;
  const int chunk = blockIdx.x, dgrp = blockIdx.y, b = blockIdx.z;
  const int d = (dgrp << 8) + tid;
  float A[16];
#pragma unroll
  for (int q = 0; q < 4; ++q) {
    f32x4 v = *(const f32x4*)(Alog + d * 16 + q * 4);
    A[q * 4 + 0] = -__expf(v[0]);
    A[q * 4 + 1] = -__expf(v[1]);
    A[q * 4 + 2] = -__expf(v[2]);
    A[q * 4 + 3] = -__expf(v[3]);
  }
  bool fastl = true;
#pragma unroll
  for (int n = 1; n < 16; ++n)
    fastl = fastl && (fabsf(A[n] - (n + 1) * A[0]) <= 1e-4f * (float)(n + 1));
  const bool fast = (__ballot(fastl) == ~0ull);

  const int base = b * 2048 + chunk * 128;
  const float* dtp = dt + (size_t)base * 4096 + d;
  const u16* up = ub + (size_t)base * 4096 + d;
  const float* Bp = ssmp + (size_t)base * 256 + 128;  // wave-uniform

  float s[16] = {};
  float dtsum = 0.f;
  float cdt[8], cu[8], ndt[8] = {}, nu[8] = {};
#pragma unroll
  for (int j = 0; j < 8; ++j) {
    cdt[j] = dtp[j * 4096];
    cu[j] = bf2f(up[j * 4096]);
  }
  for (int l0 = 0; l0 < 128; l0 += 8) {
    if (l0 + 8 < 128) {
      int o = (l0 + 8) * 4096;
#pragma unroll
      for (int j = 0; j < 8; ++j) {
        ndt[j] = dtp[o + j * 4096];
        nu[j] = bf2f(up[o + j * 4096]);
      }
    }
    if (fast) {
#pragma unroll
      for (int j = 0; j < 8; ++j) {
        float e1 = __expf(cdt[j] * A[0]);
        float x = cdt[j] * cu[j];
        const float* Bl = Bp + (l0 + j) * 256;
        f32x4 B0 = *(const f32x4*)(Bl);
        f32x4 B1 = *(const f32x4*)(Bl + 4);
        f32x4 B2 = *(const f32x4*)(Bl + 8);
        f32x4 B3 = *(const f32x4*)(Bl + 12);
        float p = 1.f;
#pragma unroll
        for (int n = 0; n < 16; ++n) {
          p *= e1;
          float Bn = (n < 4) ? B0[n & 3] : (n < 8) ? B1[n & 3] : (n < 12) ? B2[n & 3] : B3[n & 3];
          s[n] = fmaf(p, s[n], x * Bn);
        }
        dtsum += cdt[j];
      }
    } else {
#pragma unroll
      for (int j = 0; j < 8; ++j) {
        float x = cdt[j] * cu[j];
        const float* Bl = Bp + (l0 + j) * 256;
        f32x4 B0 = *(const f32x4*)(Bl);
        f32x4 B1 = *(const f32x4*)(Bl + 4);
        f32x4 B2 = *(const f32x4*)(Bl + 8);
        f32x4 B3 = *(const f32x4*)(Bl + 12);
#pragma unroll
        for (int n = 0; n < 16; ++n) {
          float e = __expf(cdt[j] * A[n]);
          float Bn = (n < 4) ? B0[n & 3] : (n < 8) ? B1[n & 3] : (n < 12) ? B2[n & 3] : B3[n & 3];
          s[n] = fmaf(e, s[n], x * Bn);
        }
        dtsum += cdt[j];
      }
    }
#pragma unroll
    for (int j = 0; j < 8; ++j) { cdt[j] = ndt[j]; cu[j] = nu[j]; }
  }
  // summary layout: [b][d][chunk][n]
  size_t o = (((size_t)(b * 4096 + d)) * 16 + chunk) * 16;
#pragma unroll
  for (int n = 0; n < 16; ++n) {
    Pout[o + n] = __expf(dtsum * A[n]);
    Sout[o + n] = s[n];
  }
}

__global__ __launch_bounds__(256) void scan_y(
    const float* __restrict__ dt, const u16* __restrict__ ub,
    const float* __restrict__ ssmp, const u16* __restrict__ gs,
    const float* __restrict__ Alog, const float* __restrict__ Dv,
    const float* __restrict__ Pin, const float* __restrict__ Sin,
    u16* __restrict__ yb) {
  const int tid = threadIdx.x;
  const int chunk = blockIdx.x, dgrp = blockIdx.y, b = blockIdx.z;
  const int d = (dgrp << 8) + tid;
  float A[16];
#pragma unroll
  for (int q = 0; q < 4; ++q) {
    f32x4 v = *(const f32x4*)(Alog + d * 16 + q * 4);
    A[q * 4 + 0] = -__expf(v[0]);
    A[q * 4 + 1] = -__expf(v[1]);
    A[q * 4 + 2] = -__expf(v[2]);
    A[q * 4 + 3] = -__expf(v[3]);
  }
  bool fastl = true;
#pragma unroll
  for (int n = 1; n < 16; ++n)
    fastl = fastl && (fabsf(A[n] - (n + 1) * A[0]) <= 1e-4f * (float)(n + 1));
  const bool fast = (__ballot(fastl) == ~0ull);
  const float Dd = Dv[d];

  const int base = b * 2048 + chunk * 128;
  const float* dtp = dt + (size_t)base * 4096 + d;
  const u16* up = ub + (size_t)base * 4096 + d;
  const u16* gp = gs + (size_t)base * 4096 + d;
  const float* Bp = ssmp + (size_t)base * 256 + 128;  // wave-uniform; C at +16
  u16* yo = yb + (size_t)base * 4096 + d;

  // fold prior chunk summaries into initial state
  float s[16] = {};
  {
    size_t po = ((size_t)(b * 4096 + d)) * 256;  // *16 chunks *16 n
    for (int k = 0; k < chunk; ++k) {
      const float* Pk = Pin + po + k * 16;
      const float* Sk = Sin + po + k * 16;
#pragma unroll
      for (int q = 0; q < 4; ++q) {
        f32x4 P = *(const f32x4*)(Pk + 4 * q);
        f32x4 S = *(const f32x4*)(Sk + 4 * q);
        s[4 * q + 0] = fmaf(P[0], s[4 * q + 0], S[0]);
        s[4 * q + 1] = fmaf(P[1], s[4 * q + 1], S[1]);
        s[4 * q + 2] = fmaf(P[2], s[4 * q + 2], S[2]);
        s[4 * q + 3] = fmaf(P[3], s[4 * q + 3], S[3]);
      }
    }
  }

  float cdt[8], cu[8], cg[8], ndt[8] = {}, nu[8] = {}, ng[8] = {};
#pragma unroll
  for (int j = 0; j < 8; ++j) {
    cdt[j] = dtp[j * 4096];
    cu[j] = bf2f(up[j * 4096]);
    cg[j] = bf2f(gp[j * 4096]);
  }
  for (int l0 = 0; l0 < 128; l0 += 8) {
    if (l0 + 8 < 128) {
      int o = (l0 + 8) * 4096;
#pragma unroll
      for (int j = 0; j < 8; ++j) {
        ndt[j] = dtp[o + j * 4096];
        nu[j] = bf2f(up[o + j * 4096]);
        ng[j] = bf2f(gp[o + j * 4096]);
      }
    }
    if (fast) {
#pragma unroll
      for (int j = 0; j < 8; ++j) {
        float e1 = __expf(cdt[j] * A[0]);
        float x = cdt[j] * cu[j];
        const float* Bl = Bp + (l0 + j) * 256;
        f32x4 B0 = *(const f32x4*)(Bl);
        f32x4 B1 = *(const f32x4*)(Bl + 4);
        f32x4 B2 = *(const f32x4*)(Bl + 8);
        f32x4 B3 = *(const f32x4*)(Bl + 12);
        f32x4 C0 = *(const f32x4*)(Bl + 16);
        f32x4 C1 = *(const f32x4*)(Bl + 20);
        f32x4 C2 = *(const f32x4*)(Bl + 24);
        f32x4 C3 = *(const f32x4*)(Bl + 28);
        float p = 1.f;
        float y0 = 0.f, y1 = 0.f, y2 = 0.f, y3 = 0.f;
#pragma unroll
        for (int n = 0; n < 16; ++n) {
          p *= e1;
          float Bn = (n < 4) ? B0[n & 3] : (n < 8) ? B1[n & 3] : (n < 12) ? B2[n & 3] : B3[n & 3];
          float Cn = (n < 4) ? C0[n & 3] : (n < 8) ? C1[n & 3] : (n < 12) ? C2[n & 3] : C3[n & 3];
          s[n] = fmaf(p, s[n], x * Bn);
          if (n < 4) y0 = fmaf(s[n], Cn, y0);
          else if (n < 8) y1 = fmaf(s[n], Cn, y1);
          else if (n < 12) y2 = fmaf(s[n], Cn, y2);
          else y3 = fmaf(s[n], Cn, y3);
        }
        float y = (y0 + y1) + (y2 + y3);
        yo[(l0 + j) * 4096] = f2bf((y + cu[j] * Dd) * cg[j]);
      }
    } else {
#pragma unroll
      for (int j = 0; j < 8; ++j) {
        float x = cdt[j] * cu[j];
        const float* Bl = Bp + (l0 + j) * 256;
        f32x4 B0 = *(const f32x4*)(Bl);
        f32x4 B1 = *(const f32x4*)(Bl + 4);
        f32x4 B2 = *(const f32x4*)(Bl + 8);
        f32x4 B3 = *(const f32x4*)(Bl + 12);
        f32x4 C0 = *(const f32x4*)(Bl + 16);
        f32x4 C1 = *(const f32x4*)(Bl + 20);
        f32x4 C2 = *(const f32x4*)(Bl + 24);
        f32x4 C3 = *(const f32x4*)(Bl + 28);
        float y0 = 0.f, y1 = 0.f, y2 = 0.f, y3 = 0.f;
#pragma unroll
        for (int n = 0; n < 16; ++n) {
          float e = __expf(cdt[j] * A[n]);
          float Bn = (n < 4) ? B0[n & 3] : (n < 8) ? B1[n & 3] : (n < 12) ? B2[n & 3] : B3[n & 3];
          float Cn = (n < 4) ? C0[n & 3] : (n < 8) ? C1[n & 3] : (n < 12) ? C2[n & 3] : C3[n & 3];
          s[n] = fmaf(e, s[n], x * Bn);
          if (n < 4) y0 = fmaf(s[n], Cn, y0);
          else if (n < 8) y1 = fmaf(s[n], Cn, y1);
          else if (n < 12) y2 = fmaf(s[n], Cn, y2);
          else y3 = fmaf(s[n], Cn, y3);
        }
        float y = (y0 + y1) + (y2 + y3);
        yo[(l0 + j) * 4096] = f2bf((y + cu[j] * Dd) * cg[j]);
      }
    }
#pragma unroll
    for (int j = 0; j < 8; ++j) { cdt[j] = ndt[j]; cu[j] = nu[j]; cg[j] = ng[j]; }
  }
}

extern "C" void kernel_launch(void* const* d_in, const int* in_sizes, int n_in,
                              void* d_out, int out_size, void* d_ws,
                              size_t ws_size, hipStream_t stream) {
  (void)in_sizes; (void)n_in; (void)out_size; (void)ws_size;
  const float* hs = (const float*)d_in[0];    // (2,2048,2048)
  const float* wIn = (const float*)d_in[1];   // (8192,2048)
  const float* cw = (const float*)d_in[2];    // (4096,1,4)
  const float* cb = (const float*)d_in[3];    // (4096)
  const float* wX = (const float*)d_in[4];    // (160,4096)
  const float* wDt = (const float*)d_in[5];   // (4096,128)
  const float* bDt = (const float*)d_in[6];   // (4096)
  const float* Alog = (const float*)d_in[7];  // (4096,16)
  const float* Dv = (const float*)d_in[8];    // (4096)
  const float* wOut = (const float*)d_in[9];  // (2048,4096)

  // ---- workspace layout (byte offsets, peak 168 MB) -----------------------
  const size_t MB = 1ull << 20;
  char* w = (char*)d_ws;
  u16* Xb = (u16*)(w + 0 * MB);
  u16* Winb = (u16*)(w + 16 * MB);
  u16* Pu = (u16*)(w + 48 * MB);
  float* DtF = (float*)(w + 0 * MB);
  u16* Yb = (u16*)(w + 64 * MB);
  u16* Ub = (u16*)(w + 96 * MB);
  u16* Wxb = (u16*)(w + 128 * MB);
  float* Smp = (float*)(w + 130 * MB);
  u16* Dtrb = (u16*)(w + 134 * MB);
  u16* Wdtb = (u16*)(w + 135 * MB);
  u16* Wob = (u16*)(w + 136 * MB);
  float* Pchk = (float*)(w + 152 * MB);
  float* Schk = (float*)(w + 160 * MB);
  u16* Pg = (u16*)d_out;  // silu(gate) bf16 lives in d_out until step 8

  // step 1: weight / input converts
  cvt_bf16<<<8192, 256, 0, stream>>>(hs, Xb, 2097152);
  cvt_bf16<<<16384, 256, 0, stream>>>(wIn, Winb, 4194304);
  cvt_xw<<<1024, 256, 0, stream>>>(wX, Wxb);
  cvt_bf16<<<512, 256, 0, stream>>>(wDt, Wdtb, 131072);
  cvt_bf16<<<8192, 256, 0, stream>>>(wOut, Wob, 2097152);

  // step 2: in_proj (u half plain bf16; gate half fused silu)
  gemm_bt<1><<<dim3(32, 32), 256, 0, stream>>>(Xb, Winb, Pu, nullptr, 2048, 4096);
  gemm_bt<2><<<dim3(32, 32), 256, 0, stream>>>(Xb, Winb + 4096L * 2048, Pg, nullptr, 2048, 4096);
  // step 3: depthwise conv + silu
  conv_silu<<<16384, 256, 0, stream>>>(Pu, cw, cb, Ub);
  // step 4: x_proj (N padded 160 -> 256)
  gemm_bt<0><<<dim3(2, 32), 256, 0, stream>>>(Ub, Wxb, Smp, nullptr, 4096, 256);
  // step 5: extract dt_r as bf16
  cvt_dtr<<<512, 256, 0, stream>>>(Smp, Dtrb);
  // step 6: dt_proj with fused softplus(acc + bias) -> fp32 dt
  gemm_bt<3><<<dim3(32, 32), 256, 0, stream>>>(Dtrb, Wdtb, DtF, bDt, 128, 4096);
  // step 7: chunked selective scan (pass 1: summaries, pass 2: y)
  scan_part<<<dim3(16, 16, 2), 256, 0, stream>>>(DtF, Ub, Smp, Alog, Pchk, Schk);
  scan_y<<<dim3(16, 16, 2), 256, 0, stream>>>(DtF, Ub, Smp, Pg, Alog, Dv, Pchk, Schk, Yb);
  // step 8: out_proj -> fp32 output (overwrites Pg/d_out entirely)
  gemm_bt<0><<<dim3(16, 32), 256, 0, stream>>>(Yb, Wob, (float*)d_out, nullptr, 4096, 2048);
}

// Round 7
// 687.842 us; speedup vs baseline: 2.9243x; 1.1800x over previous
//
#include <hip/hip_runtime.h>

typedef unsigned int u32;
typedef unsigned short u16;
typedef float f32x4 __attribute__((ext_vector_type(4)));
typedef u16 us4 __attribute__((ext_vector_type(4)));
typedef u16 us8 __attribute__((ext_vector_type(8)));
typedef __bf16 bf16x8 __attribute__((ext_vector_type(8)));

__device__ __forceinline__ u16 f2bf(float f) {
  u32 u = __builtin_bit_cast(u32, f);
  u += 0x7fffu + ((u >> 16) & 1u);
  return (u16)(u >> 16);
}
__device__ __forceinline__ float bf2f(u16 h) {
  u32 u = ((u32)h) << 16;
  return __builtin_bit_cast(float, u);
}
__device__ __forceinline__ void async16(const void* g, void* l) {
  __builtin_amdgcn_global_load_lds((const __attribute__((address_space(1))) void*)g,
                                   (__attribute__((address_space(3))) void*)l, 16, 0, 0);
}

// ---------------------------------------------------------------------------
// C = A * B^T.  A: M x K bf16 row-major. B: N x K bf16 row-major.
// BK=64, XOR-8 swizzled LDS (conflict-free ds_read_b128): LDS slot s holds
// global chunk (s&7)^((s>>3)&7) of row s>>3; row stride 128 B = 32 banks.
// ACT: 0 = fp32 store, 1 = bf16, 2 = bf16 silu, 3 = fp32 softplus(+bias),
// 5 = in_proj dual (col<4096 -> bf16 Cv; col>=4096 -> silu bf16 into `bias`
//     reinterpreted as u16*).
// SPLITK: blockIdx.z takes K/gridDim.z slice, C offset z*gridDim.y*128*ldc.
// ---------------------------------------------------------------------------
template <int ACT, bool SPLITK = false>
__global__ __launch_bounds__(256) void gemm_bt(const u16* __restrict__ A,
                                               const u16* __restrict__ B,
                                               void* __restrict__ Cv,
                                               const float* __restrict__ bias,
                                               int K, int ldc) {
  __shared__ __align__(16) u16 As[128 * 64];
  __shared__ __align__(16) u16 Bs[128 * 64];
  const int tid = threadIdx.x;
  const int lane = tid & 63;
  const int wave = tid >> 6;
  const int lm = lane & 15;
  const int quad = lane >> 4;
  const int wm = (wave >> 1) << 6;
  const int wn = (wave & 1) << 6;
  const long rowBase = (long)blockIdx.y << 7;
  const long colBase = (long)blockIdx.x << 7;

  int kStart = 0, kEnd = K;
  if constexpr (SPLITK) {
    int kn = K / gridDim.z;
    kStart = blockIdx.z * kn;
    kEnd = kStart + kn;
  }

  // staging: slot s = tid + 256*c; row (s>>3), swizzled chunk fixed per thread
  const int rr = tid >> 3;
  const int qg = (tid & 7) ^ (rr & 7);
  const u16* Ag = A + (rowBase + rr) * (long)K + qg * 8;
  const u16* Bg = B + (colBase + rr) * (long)K + qg * 8;
  u16* Al = As + tid * 8;
  u16* Bl = Bs + tid * 8;

  f32x4 acc[4][4] = {};
  const int l7 = lm & 7;

  for (int k0 = kStart; k0 < kEnd; k0 += 64) {
#pragma unroll
    for (int c = 0; c < 4; ++c) {
      async16(Ag + 32L * c * K + k0, Al + 2048 * c);
      async16(Bg + 32L * c * K + k0, Bl + 2048 * c);
    }
    __syncthreads();
#pragma unroll
    for (int h = 0; h < 2; ++h) {
      const int xa = ((h * 4 + quad) ^ l7) * 8;
      us8 af[4], bfr[4];
#pragma unroll
      for (int i = 0; i < 4; ++i)
        af[i] = *(const us8*)(As + (wm + i * 16 + lm) * 64 + xa);
#pragma unroll
      for (int i = 0; i < 4; ++i)
        bfr[i] = *(const us8*)(Bs + (wn + i * 16 + lm) * 64 + xa);
#pragma unroll
      for (int i = 0; i < 4; ++i)
#pragma unroll
        for (int j = 0; j < 4; ++j)
          acc[i][j] = __builtin_amdgcn_mfma_f32_16x16x32_bf16(
              __builtin_bit_cast(bf16x8, af[i]), __builtin_bit_cast(bf16x8, bfr[j]),
              acc[i][j], 0, 0, 0);
    }
    __syncthreads();
  }

  float* Cf = (float*)Cv;
  if constexpr (SPLITK)
    Cf += (size_t)blockIdx.z * ((size_t)gridDim.y * 128 * ldc);

#pragma unroll
  for (int i = 0; i < 4; ++i)
#pragma unroll
    for (int j = 0; j < 4; ++j)
#pragma unroll
      for (int r = 0; r < 4; ++r) {
        long row = rowBase + wm + i * 16 + quad * 4 + r;
        long col = colBase + wn + j * 16 + lm;
        float v = acc[i][j][r];
        if constexpr (ACT == 0) {
          Cf[row * ldc + col] = v;
        } else if constexpr (ACT == 1) {
          ((u16*)Cv)[row * ldc + col] = f2bf(v);
        } else if constexpr (ACT == 2) {
          float s = v / (1.f + __expf(-v));
          ((u16*)Cv)[row * ldc + col] = f2bf(s);
        } else if constexpr (ACT == 3) {
          v += bias[col];
          float sp = (v > 20.f) ? v : log1pf(__expf(v));
          Cf[row * ldc + col] = sp;
        } else {  // ACT == 5: dual in_proj epilogue (block-uniform branch)
          if (colBase < 4096) {
            ((u16*)Cv)[row * 4096 + col] = f2bf(v);
          } else {
            float s = v / (1.f + __expf(-v));
            ((u16*)(size_t)bias)[row * 4096 + (col - 4096)] = f2bf(s);
          }
        }
      }
}

// fp32 -> bf16, 4 elems/thread
__global__ __launch_bounds__(256) void cvt_bf16(const float* __restrict__ in,
                                                u16* __restrict__ out, int n4) {
  int i = blockIdx.x * 256 + threadIdx.x;
  if (i >= n4) return;
  f32x4 v = ((const f32x4*)in)[i];
  us4 o;
  o[0] = f2bf(v[0]); o[1] = f2bf(v[1]); o[2] = f2bf(v[2]); o[3] = f2bf(v[3]);
  ((us4*)out)[i] = o;
}

// x_proj_w (160 x 4096) -> bf16 padded to (256 x 4096), pad rows zero
__global__ __launch_bounds__(256) void cvt_xw(const float* __restrict__ in,
                                              u16* __restrict__ out) {
  int i = blockIdx.x * 256 + threadIdx.x;
  int row = (i << 2) >> 12;
  us4 o;
  if (row < 160) {
    f32x4 v = ((const f32x4*)in)[i];
    o[0] = f2bf(v[0]); o[1] = f2bf(v[1]); o[2] = f2bf(v[2]); o[3] = f2bf(v[3]);
  } else {
    o[0] = 0; o[1] = 0; o[2] = 0; o[3] = 0;
  }
  ((us4*)out)[i] = o;
}

// reduce 4 split-K partials of x_proj -> Smp fp32 (4096 x 256); also emit
// dt_r bf16 (first 128 cols) for dt_proj.
__global__ __launch_bounds__(256) void xp_reduce(const float* __restrict__ part,
                                                 float* __restrict__ smp,
                                                 u16* __restrict__ dtrb) {
  int i = blockIdx.x * 256 + threadIdx.x;  // 262144 total
  const f32x4* p = (const f32x4*)part;
  f32x4 v = p[i];
  v += p[i + 262144];
  v += p[i + 524288];
  v += p[i + 786432];
  ((f32x4*)smp)[i] = v;
  int e = i << 2;
  int c = e & 255;
  if (c < 128) {
    int t = e >> 8;
    us4 o;
    o[0] = f2bf(v[0]); o[1] = f2bf(v[1]); o[2] = f2bf(v[2]); o[3] = f2bf(v[3]);
    *(us4*)(dtrb + t * 128 + c) = o;
  }
}

// depthwise causal conv (K=4) + bias + SiLU
__global__ __launch_bounds__(256) void conv_silu(const u16* __restrict__ U,
                                                 const float* __restrict__ cw,
                                                 const float* __restrict__ cb,
                                                 u16* __restrict__ out) {
  int i = blockIdx.x * 256 + threadIdx.x;
  int t = i >> 10;
  int d4 = (i & 1023) << 2;
  int l = t & 2047;
  float w[4][4];
#pragma unroll
  for (int j = 0; j < 4; ++j) {
    f32x4 wv = *(const f32x4*)(cw + (d4 + j) * 4);
    w[j][0] = wv[0]; w[j][1] = wv[1]; w[j][2] = wv[2]; w[j][3] = wv[3];
  }
  float r[4] = {cb[d4], cb[d4 + 1], cb[d4 + 2], cb[d4 + 3]};
#pragma unroll
  for (int k = 0; k < 4; ++k) {
    int ll = l - 3 + k;
    if (ll >= 0) {
      us4 xv = *(const us4*)(U + (size_t)(t - 3 + k) * 4096 + d4);
      r[0] += w[0][k] * bf2f(xv[0]);
      r[1] += w[1][k] * bf2f(xv[1]);
      r[2] += w[2][k] * bf2f(xv[2]);
      r[3] += w[3][k] * bf2f(xv[3]);
    }
  }
  us4 o;
#pragma unroll
  for (int j = 0; j < 4; ++j) {
    float v = r[j];
    float s = v / (1.f + __expf(-v));
    o[j] = f2bf(s);
  }
  *(us4*)(out + (size_t)t * 4096 + d4) = o;
}

// ---------------------------------------------------------------------------
// Chunked selective scan, channel-per-thread layout (see round-6 notes).
// ---------------------------------------------------------------------------
__global__ __launch_bounds__(256) void scan_part(
    const float* __restrict__ dt, const u16* __restrict__ ub,
    const float* __restrict__ ssmp, const float* __restrict__ Alog,
    float* __restrict__ Pout, float* __restrict__ Sout) {
  const int tid = threadIdx.x;
  const int chunk = blockIdx.x, dgrp = blockIdx.y, b = blockIdx.z;
  const int d = (dgrp << 8) + tid;
  float A[16];
#pragma unroll
  for (int q = 0; q < 4; ++q) {
    f32x4 v = *(const f32x4*)(Alog + d * 16 + q * 4);
    A[q * 4 + 0] = -__expf(v[0]);
    A[q * 4 + 1] = -__expf(v[1]);
    A[q * 4 + 2] = -__expf(v[2]);
    A[q * 4 + 3] = -__expf(v[3]);
  }
  bool fastl = true;
#pragma unroll
  for (int n = 1; n < 16; ++n)
    fastl = fastl && (fabsf(A[n] - (n + 1) * A[0]) <= 1e-4f * (float)(n + 1));
  const bool fast = (__ballot(fastl) == ~0ull);

  const int base = b * 2048 + chunk * 128;
  const float* dtp = dt + (size_t)base * 4096 + d;
  const u16* up = ub + (size_t)base * 4096 + d;
  const float* Bp = ssmp + (size_t)base * 256 + 128;  // wave-uniform

  float s[16] = {};
  float dtsum = 0.f;
  float cdt[8], cu[8], ndt[8] = {}, nu[8] = {};
#pragma unroll
  for (int j = 0; j < 8; ++j) {
    cdt[j] = dtp[j * 4096];
    cu[j] = bf2f(up[j * 4096]);
  }
  for (int l0 = 0; l0 < 128; l0 += 8) {
    if (l0 + 8 < 128) {
      int o = (l0 + 8) * 4096;
#pragma unroll
      for (int j = 0; j < 8; ++j) {
        ndt[j] = dtp[o + j * 4096];
        nu[j] = bf2f(up[o + j * 4096]);
      }
    }
    if (fast) {
#pragma unroll
      for (int j = 0; j < 8; ++j) {
        float e1 = __expf(cdt[j] * A[0]);
        float x = cdt[j] * cu[j];
        const float* Bl = Bp + (l0 + j) * 256;
        f32x4 B0 = *(const f32x4*)(Bl);
        f32x4 B1 = *(const f32x4*)(Bl + 4);
        f32x4 B2 = *(const f32x4*)(Bl + 8);
        f32x4 B3 = *(const f32x4*)(Bl + 12);
        float p = 1.f;
#pragma unroll
        for (int n = 0; n < 16; ++n) {
          p *= e1;
          float Bn = (n < 4) ? B0[n & 3] : (n < 8) ? B1[n & 3] : (n < 12) ? B2[n & 3] : B3[n & 3];
          s[n] = fmaf(p, s[n], x * Bn);
        }
        dtsum += cdt[j];
      }
    } else {
#pragma unroll
      for (int j = 0; j < 8; ++j) {
        float x = cdt[j] * cu[j];
        const float* Bl = Bp + (l0 + j) * 256;
        f32x4 B0 = *(const f32x4*)(Bl);
        f32x4 B1 = *(const f32x4*)(Bl + 4);
        f32x4 B2 = *(const f32x4*)(Bl + 8);
        f32x4 B3 = *(const f32x4*)(Bl + 12);
#pragma unroll
        for (int n = 0; n < 16; ++n) {
          float e = __expf(cdt[j] * A[n]);
          float Bn = (n < 4) ? B0[n & 3] : (n < 8) ? B1[n & 3] : (n < 12) ? B2[n & 3] : B3[n & 3];
          s[n] = fmaf(e, s[n], x * Bn);
        }
        dtsum += cdt[j];
      }
    }
#pragma unroll
    for (int j = 0; j < 8; ++j) { cdt[j] = ndt[j]; cu[j] = nu[j]; }
  }
  size_t o = (((size_t)(b * 4096 + d)) * 16 + chunk) * 16;
#pragma unroll
  for (int n = 0; n < 16; ++n) {
    Pout[o + n] = __expf(dtsum * A[n]);
    Sout[o + n] = s[n];
  }
}

__global__ __launch_bounds__(256) void scan_y(
    const float* __restrict__ dt, const u16* __restrict__ ub,
    const float* __restrict__ ssmp, const u16* __restrict__ gs,
    const float* __restrict__ Alog, const float* __restrict__ Dv,
    const float* __restrict__ Pin, const float* __restrict__ Sin,
    u16* __restrict__ yb) {
  const int tid = threadIdx.x;
  const int chunk = blockIdx.x, dgrp = blockIdx.y, b = blockIdx.z;
  const int d = (dgrp << 8) + tid;
  float A[16];
#pragma unroll
  for (int q = 0; q < 4; ++q) {
    f32x4 v = *(const f32x4*)(Alog + d * 16 + q * 4);
    A[q * 4 + 0] = -__expf(v[0]);
    A[q * 4 + 1] = -__expf(v[1]);
    A[q * 4 + 2] = -__expf(v[2]);
    A[q * 4 + 3] = -__expf(v[3]);
  }
  bool fastl = true;
#pragma unroll
  for (int n = 1; n < 16; ++n)
    fastl = fastl && (fabsf(A[n] - (n + 1) * A[0]) <= 1e-4f * (float)(n + 1));
  const bool fast = (__ballot(fastl) == ~0ull);
  const float Dd = Dv[d];

  const int base = b * 2048 + chunk * 128;
  const float* dtp = dt + (size_t)base * 4096 + d;
  const u16* up = ub + (size_t)base * 4096 + d;
  const u16* gp = gs + (size_t)base * 4096 + d;
  const float* Bp = ssmp + (size_t)base * 256 + 128;
  u16* yo = yb + (size_t)base * 4096 + d;

  float s[16] = {};
  {
    size_t po = ((size_t)(b * 4096 + d)) * 256;
    for (int k = 0; k < chunk; ++k) {
      const float* Pk = Pin + po + k * 16;
      const float* Sk = Sin + po + k * 16;
#pragma unroll
      for (int q = 0; q < 4; ++q) {
        f32x4 P = *(const f32x4*)(Pk + 4 * q);
        f32x4 S = *(const f32x4*)(Sk + 4 * q);
        s[4 * q + 0] = fmaf(P[0], s[4 * q + 0], S[0]);
        s[4 * q + 1] = fmaf(P[1], s[4 * q + 1], S[1]);
        s[4 * q + 2] = fmaf(P[2], s[4 * q + 2], S[2]);
        s[4 * q + 3] = fmaf(P[3], s[4 * q + 3], S[3]);
      }
    }
  }

  float cdt[8], cu[8], cg[8], ndt[8] = {}, nu[8] = {}, ng[8] = {};
#pragma unroll
  for (int j = 0; j < 8; ++j) {
    cdt[j] = dtp[j * 4096];
    cu[j] = bf2f(up[j * 4096]);
    cg[j] = bf2f(gp[j * 4096]);
  }
  for (int l0 = 0; l0 < 128; l0 += 8) {
    if (l0 + 8 < 128) {
      int o = (l0 + 8) * 4096;
#pragma unroll
      for (int j = 0; j < 8; ++j) {
        ndt[j] = dtp[o + j * 4096];
        nu[j] = bf2f(up[o + j * 4096]);
        ng[j] = bf2f(gp[o + j * 4096]);
      }
    }
    if (fast) {
#pragma unroll
      for (int j = 0; j < 8; ++j) {
        float e1 = __expf(cdt[j] * A[0]);
        float x = cdt[j] * cu[j];
        const float* Bl = Bp + (l0 + j) * 256;
        f32x4 B0 = *(const f32x4*)(Bl);
        f32x4 B1 = *(const f32x4*)(Bl + 4);
        f32x4 B2 = *(const f32x4*)(Bl + 8);
        f32x4 B3 = *(const f32x4*)(Bl + 12);
        f32x4 C0 = *(const f32x4*)(Bl + 16);
        f32x4 C1 = *(const f32x4*)(Bl + 20);
        f32x4 C2 = *(const f32x4*)(Bl + 24);
        f32x4 C3 = *(const f32x4*)(Bl + 28);
        float p = 1.f;
        float y0 = 0.f, y1 = 0.f, y2 = 0.f, y3 = 0.f;
#pragma unroll
        for (int n = 0; n < 16; ++n) {
          p *= e1;
          float Bn = (n < 4) ? B0[n & 3] : (n < 8) ? B1[n & 3] : (n < 12) ? B2[n & 3] : B3[n & 3];
          float Cn = (n < 4) ? C0[n & 3] : (n < 8) ? C1[n & 3] : (n < 12) ? C2[n & 3] : C3[n & 3];
          s[n] = fmaf(p, s[n], x * Bn);
          if (n < 4) y0 = fmaf(s[n], Cn, y0);
          else if (n < 8) y1 = fmaf(s[n], Cn, y1);
          else if (n < 12) y2 = fmaf(s[n], Cn, y2);
          else y3 = fmaf(s[n], Cn, y3);
        }
        float y = (y0 + y1) + (y2 + y3);
        yo[(l0 + j) * 4096] = f2bf((y + cu[j] * Dd) * cg[j]);
      }
    } else {
#pragma unroll
      for (int j = 0; j < 8; ++j) {
        float x = cdt[j] * cu[j];
        const float* Bl = Bp + (l0 + j) * 256;
        f32x4 B0 = *(const f32x4*)(Bl);
        f32x4 B1 = *(const f32x4*)(Bl + 4);
        f32x4 B2 = *(const f32x4*)(Bl + 8);
        f32x4 B3 = *(const f32x4*)(Bl + 12);
        f32x4 C0 = *(const f32x4*)(Bl + 16);
        f32x4 C1 = *(const f32x4*)(Bl + 20);
        f32x4 C2 = *(const f32x4*)(Bl + 24);
        f32x4 C3 = *(const f32x4*)(Bl + 28);
        float y0 = 0.f, y1 = 0.f, y2 = 0.f, y3 = 0.f;
#pragma unroll
        for (int n = 0; n < 16; ++n) {
          float e = __expf(cdt[j] * A[n]);
          float Bn = (n < 4) ? B0[n & 3] : (n < 8) ? B1[n & 3] : (n < 12) ? B2[n & 3] : B3[n & 3];
          float Cn = (n < 4) ? C0[n & 3] : (n < 8) ? C1[n & 3] : (n < 12) ? C2[n & 3] : C3[n & 3];
          s[n] = fmaf(e, s[n], x * Bn);
          if (n < 4) y0 = fmaf(s[n], Cn, y0);
          else if (n < 8) y1 = fmaf(s[n], Cn, y1);
          else if (n < 12) y2 = fmaf(s[n], Cn, y2);
          else y3 = fmaf(s[n], Cn, y3);
        }
        float y = (y0 + y1) + (y2 + y3);
        yo[(l0 + j) * 4096] = f2bf((y + cu[j] * Dd) * cg[j]);
      }
    }
#pragma unroll
    for (int j = 0; j < 8; ++j) { cdt[j] = ndt[j]; cu[j] = nu[j]; cg[j] = ng[j]; }
  }
}

extern "C" void kernel_launch(void* const* d_in, const int* in_sizes, int n_in,
                              void* d_out, int out_size, void* d_ws,
                              size_t ws_size, hipStream_t stream) {
  (void)in_sizes; (void)n_in; (void)out_size; (void)ws_size;
  const float* hs = (const float*)d_in[0];    // (2,2048,2048)
  const float* wIn = (const float*)d_in[1];   // (8192,2048)
  const float* cw = (const float*)d_in[2];    // (4096,1,4)
  const float* cb = (const float*)d_in[3];    // (4096)
  const float* wX = (const float*)d_in[4];    // (160,4096)
  const float* wDt = (const float*)d_in[5];   // (4096,128)
  const float* bDt = (const float*)d_in[6];   // (4096)
  const float* Alog = (const float*)d_in[7];  // (4096,16)
  const float* Dv = (const float*)d_in[8];    // (4096)
  const float* wOut = (const float*)d_in[9];  // (2048,4096)

  // ---- workspace layout (byte offsets, peak 184 MB) -----------------------
  const size_t MB = 1ull << 20;
  char* w = (char*)d_ws;
  u16* Xb = (u16*)(w + 0 * MB);
  u16* Winb = (u16*)(w + 16 * MB);
  u16* Pu = (u16*)(w + 48 * MB);
  float* DtF = (float*)(w + 0 * MB);
  u16* Yb = (u16*)(w + 64 * MB);
  u16* Ub = (u16*)(w + 96 * MB);
  u16* Wxb = (u16*)(w + 128 * MB);
  float* Smp = (float*)(w + 130 * MB);
  u16* Dtrb = (u16*)(w + 134 * MB);
  u16* Wdtb = (u16*)(w + 135 * MB);
  u16* Wob = (u16*)(w + 136 * MB);
  float* Pchk = (float*)(w + 152 * MB);
  float* Schk = (float*)(w + 160 * MB);
  float* Xpart = (float*)(w + 168 * MB);  // 4 x 4 MB split-K partials
  u16* Pg = (u16*)d_out;  // silu(gate) bf16 lives in d_out until out_proj

  // step 1: weight / input converts
  cvt_bf16<<<8192, 256, 0, stream>>>(hs, Xb, 2097152);
  cvt_bf16<<<16384, 256, 0, stream>>>(wIn, Winb, 4194304);
  cvt_xw<<<1024, 256, 0, stream>>>(wX, Wxb);
  cvt_bf16<<<512, 256, 0, stream>>>(wDt, Wdtb, 131072);
  cvt_bf16<<<8192, 256, 0, stream>>>(wOut, Wob, 2097152);

  // step 2: in_proj, single dispatch (u plain bf16 | gate silu bf16)
  gemm_bt<5><<<dim3(64, 32), 256, 0, stream>>>(Xb, Winb, Pu, (const float*)Pg, 2048, 4096);
  // step 3: depthwise conv + silu
  conv_silu<<<16384, 256, 0, stream>>>(Pu, cw, cb, Ub);
  // step 4: x_proj split-K x4 into partials, then reduce (+ dt_r extract)
  gemm_bt<0, true><<<dim3(2, 32, 4), 256, 0, stream>>>(Ub, Wxb, Xpart, nullptr, 4096, 256);
  xp_reduce<<<1024, 256, 0, stream>>>(Xpart, Smp, Dtrb);
  // step 5: dt_proj with fused softplus(acc + bias) -> fp32 dt
  gemm_bt<3><<<dim3(32, 32), 256, 0, stream>>>(Dtrb, Wdtb, DtF, bDt, 128, 4096);
  // step 6: chunked selective scan (pass 1: summaries, pass 2: y)
  scan_part<<<dim3(16, 16, 2), 256, 0, stream>>>(DtF, Ub, Smp, Alog, Pchk, Schk);
  scan_y<<<dim3(16, 16, 2), 256, 0, stream>>>(DtF, Ub, Smp, Pg, Alog, Dv, Pchk, Schk, Yb);
  // step 7: out_proj -> fp32 output (overwrites Pg/d_out entirely)
  gemm_bt<0><<<dim3(16, 32), 256, 0, stream>>>(Yb, Wob, (float*)d_out, nullptr, 4096, 2048);
}

// Round 8
// 667.095 us; speedup vs baseline: 3.0152x; 1.0311x over previous
//
#include <hip/hip_runtime.h>

typedef unsigned int u32;
typedef unsigned short u16;
typedef float f32x4 __attribute__((ext_vector_type(4)));
typedef u16 us4 __attribute__((ext_vector_type(4)));
typedef u16 us8 __attribute__((ext_vector_type(8)));
typedef __bf16 bf16x8 __attribute__((ext_vector_type(8)));

__device__ __forceinline__ u16 f2bf(float f) {
  u32 u = __builtin_bit_cast(u32, f);
  u += 0x7fffu + ((u >> 16) & 1u);
  return (u16)(u >> 16);
}
__device__ __forceinline__ float bf2f(u16 h) {
  u32 u = ((u32)h) << 16;
  return __builtin_bit_cast(float, u);
}
__device__ __forceinline__ void async16(const void* g, void* l) {
  __builtin_amdgcn_global_load_lds((const __attribute__((address_space(1))) void*)g,
                                   (__attribute__((address_space(3))) void*)l, 16, 0, 0);
}

// ---------------------------------------------------------------------------
// C = A * B^T.  A: M x K bf16 row-major. B: N x K bf16 row-major.
// BK=64, XOR-8 swizzled LDS (conflict-free ds_read_b128, verified r7:
// SQ_LDS_BANK_CONFLICT 8.4M -> 0).
// ACT: 0 = fp32 store, 1 = bf16, 2 = bf16 silu, 3 = fp32 softplus(+bias),
// 4 = bf16 softplus(+bias), 5 = in_proj dual (col<4096 -> bf16 Cv;
//     col>=4096 -> silu bf16 into `bias` reinterpreted as u16*).
// SPLITK: blockIdx.z takes K/gridDim.z slice, C offset z*gridDim.y*128*ldc.
// ---------------------------------------------------------------------------
template <int ACT, bool SPLITK = false>
__global__ __launch_bounds__(256) void gemm_bt(const u16* __restrict__ A,
                                               const u16* __restrict__ B,
                                               void* __restrict__ Cv,
                                               const float* __restrict__ bias,
                                               int K, int ldc) {
  __shared__ __align__(16) u16 As[128 * 64];
  __shared__ __align__(16) u16 Bs[128 * 64];
  const int tid = threadIdx.x;
  const int lane = tid & 63;
  const int wave = tid >> 6;
  const int lm = lane & 15;
  const int quad = lane >> 4;
  const int wm = (wave >> 1) << 6;
  const int wn = (wave & 1) << 6;
  const long rowBase = (long)blockIdx.y << 7;
  const long colBase = (long)blockIdx.x << 7;

  int kStart = 0, kEnd = K;
  if constexpr (SPLITK) {
    int kn = K / gridDim.z;
    kStart = blockIdx.z * kn;
    kEnd = kStart + kn;
  }

  const int rr = tid >> 3;
  const int qg = (tid & 7) ^ (rr & 7);
  const u16* Ag = A + (rowBase + rr) * (long)K + qg * 8;
  const u16* Bg = B + (colBase + rr) * (long)K + qg * 8;
  u16* Al = As + tid * 8;
  u16* Bl = Bs + tid * 8;

  f32x4 acc[4][4] = {};
  const int l7 = lm & 7;

  for (int k0 = kStart; k0 < kEnd; k0 += 64) {
#pragma unroll
    for (int c = 0; c < 4; ++c) {
      async16(Ag + 32L * c * K + k0, Al + 2048 * c);
      async16(Bg + 32L * c * K + k0, Bl + 2048 * c);
    }
    __syncthreads();
#pragma unroll
    for (int h = 0; h < 2; ++h) {
      const int xa = ((h * 4 + quad) ^ l7) * 8;
      us8 af[4], bfr[4];
#pragma unroll
      for (int i = 0; i < 4; ++i)
        af[i] = *(const us8*)(As + (wm + i * 16 + lm) * 64 + xa);
#pragma unroll
      for (int i = 0; i < 4; ++i)
        bfr[i] = *(const us8*)(Bs + (wn + i * 16 + lm) * 64 + xa);
#pragma unroll
      for (int i = 0; i < 4; ++i)
#pragma unroll
        for (int j = 0; j < 4; ++j)
          acc[i][j] = __builtin_amdgcn_mfma_f32_16x16x32_bf16(
              __builtin_bit_cast(bf16x8, af[i]), __builtin_bit_cast(bf16x8, bfr[j]),
              acc[i][j], 0, 0, 0);
    }
    __syncthreads();
  }

  float* Cf = (float*)Cv;
  if constexpr (SPLITK)
    Cf += (size_t)blockIdx.z * ((size_t)gridDim.y * 128 * ldc);

#pragma unroll
  for (int i = 0; i < 4; ++i)
#pragma unroll
    for (int j = 0; j < 4; ++j)
#pragma unroll
      for (int r = 0; r < 4; ++r) {
        long row = rowBase + wm + i * 16 + quad * 4 + r;
        long col = colBase + wn + j * 16 + lm;
        float v = acc[i][j][r];
        if constexpr (ACT == 0) {
          Cf[row * ldc + col] = v;
        } else if constexpr (ACT == 1) {
          ((u16*)Cv)[row * ldc + col] = f2bf(v);
        } else if constexpr (ACT == 2) {
          float s = v / (1.f + __expf(-v));
          ((u16*)Cv)[row * ldc + col] = f2bf(s);
        } else if constexpr (ACT == 3) {
          v += bias[col];
          float sp = (v > 20.f) ? v : log1pf(__expf(v));
          Cf[row * ldc + col] = sp;
        } else if constexpr (ACT == 4) {
          v += bias[col];
          float sp = (v > 20.f) ? v : log1pf(__expf(v));
          ((u16*)Cv)[row * ldc + col] = f2bf(sp);
        } else {  // ACT == 5: dual in_proj epilogue (block-uniform branch)
          if (colBase < 4096) {
            ((u16*)Cv)[row * 4096 + col] = f2bf(v);
          } else {
            float s = v / (1.f + __expf(-v));
            ((u16*)(size_t)bias)[row * 4096 + (col - 4096)] = f2bf(s);
          }
        }
      }
}

// one fused fp32->bf16 convert for all weight/input tensors
__device__ __forceinline__ void cvt4(const float* __restrict__ in,
                                     u16* __restrict__ out, int i) {
  f32x4 v = ((const f32x4*)in)[i];
  us4 o;
  o[0] = f2bf(v[0]); o[1] = f2bf(v[1]); o[2] = f2bf(v[2]); o[3] = f2bf(v[3]);
  ((us4*)out)[i] = o;
}
// total vec4s: hs 2097152 | wIn 4194304 | wOut 2097152 | wDt 131072 | xw 262144
__global__ __launch_bounds__(256) void cvt_all(
    const float* __restrict__ hs, const float* __restrict__ wIn,
    const float* __restrict__ wOut, const float* __restrict__ wDt,
    const float* __restrict__ wX, u16* __restrict__ Xb, u16* __restrict__ Winb,
    u16* __restrict__ Wob, u16* __restrict__ Wdtb, u16* __restrict__ Wxb) {
  int i = blockIdx.x * 256 + threadIdx.x;
  if (i < 2097152) { cvt4(hs, Xb, i); return; }
  i -= 2097152;
  if (i < 4194304) { cvt4(wIn, Winb, i); return; }
  i -= 4194304;
  if (i < 2097152) { cvt4(wOut, Wob, i); return; }
  i -= 2097152;
  if (i < 131072) { cvt4(wDt, Wdtb, i); return; }
  i -= 131072;
  if (i >= 262144) return;
  int row = (i << 2) >> 12;
  us4 o;
  if (row < 160) {
    f32x4 v = ((const f32x4*)wX)[i];
    o[0] = f2bf(v[0]); o[1] = f2bf(v[1]); o[2] = f2bf(v[2]); o[3] = f2bf(v[3]);
  } else {
    o[0] = 0; o[1] = 0; o[2] = 0; o[3] = 0;
  }
  ((us4*)Wxb)[i] = o;
}

// reduce 4 split-K partials of x_proj -> Smp fp32 (4096 x 256); also emit
// dt_r bf16 (first 128 cols) for dt_proj.
__global__ __launch_bounds__(256) void xp_reduce(const float* __restrict__ part,
                                                 float* __restrict__ smp,
                                                 u16* __restrict__ dtrb) {
  int i = blockIdx.x * 256 + threadIdx.x;  // 262144 total
  const f32x4* p = (const f32x4*)part;
  f32x4 v = p[i];
  v += p[i + 262144];
  v += p[i + 524288];
  v += p[i + 786432];
  ((f32x4*)smp)[i] = v;
  int e = i << 2;
  int c = e & 255;
  if (c < 128) {
    int t = e >> 8;
    us4 o;
    o[0] = f2bf(v[0]); o[1] = f2bf(v[1]); o[2] = f2bf(v[2]); o[3] = f2bf(v[3]);
    *(us4*)(dtrb + t * 128 + c) = o;
  }
}

// depthwise causal conv (K=4) + bias + SiLU
__global__ __launch_bounds__(256) void conv_silu(const u16* __restrict__ U,
                                                 const float* __restrict__ cw,
                                                 const float* __restrict__ cb,
                                                 u16* __restrict__ out) {
  int i = blockIdx.x * 256 + threadIdx.x;
  int t = i >> 10;
  int d4 = (i & 1023) << 2;
  int l = t & 2047;
  float w[4][4];
#pragma unroll
  for (int j = 0; j < 4; ++j) {
    f32x4 wv = *(const f32x4*)(cw + (d4 + j) * 4);
    w[j][0] = wv[0]; w[j][1] = wv[1]; w[j][2] = wv[2]; w[j][3] = wv[3];
  }
  float r[4] = {cb[d4], cb[d4 + 1], cb[d4 + 2], cb[d4 + 3]};
#pragma unroll
  for (int k = 0; k < 4; ++k) {
    int ll = l - 3 + k;
    if (ll >= 0) {
      us4 xv = *(const us4*)(U + (size_t)(t - 3 + k) * 4096 + d4);
      r[0] += w[0][k] * bf2f(xv[0]);
      r[1] += w[1][k] * bf2f(xv[1]);
      r[2] += w[2][k] * bf2f(xv[2]);
      r[3] += w[3][k] * bf2f(xv[3]);
    }
  }
  us4 o;
#pragma unroll
  for (int j = 0; j < 4; ++j) {
    float v = r[j];
    float s = v / (1.f + __expf(-v));
    o[j] = f2bf(s);
  }
  *(us4*)(out + (size_t)t * 4096 + d4) = o;
}

// ---------------------------------------------------------------------------
// Chunked selective scan, channel-per-thread layout.  dt is bf16 (softplus
// fused in dt_proj).  Chunk summaries in [b][chunk][n][d] layout so both the
// scan_part stores and the scan_y fold loads are wave-coalesced.
// ---------------------------------------------------------------------------
__global__ __launch_bounds__(256) void scan_part(
    const u16* __restrict__ dt, const u16* __restrict__ ub,
    const float* __restrict__ ssmp, const float* __restrict__ Alog,
    float* __restrict__ Pout, float* __restrict__ Sout) {
  const int tid = threadIdx.x;
  const int chunk = blockIdx.x, dgrp = blockIdx.y, b = blockIdx.z;
  const int d = (dgrp << 8) + tid;
  float A[16];
#pragma unroll
  for (int q = 0; q < 4; ++q) {
    f32x4 v = *(const f32x4*)(Alog + d * 16 + q * 4);
    A[q * 4 + 0] = -__expf(v[0]);
    A[q * 4 + 1] = -__expf(v[1]);
    A[q * 4 + 2] = -__expf(v[2]);
    A[q * 4 + 3] = -__expf(v[3]);
  }
  bool fastl = true;
#pragma unroll
  for (int n = 1; n < 16; ++n)
    fastl = fastl && (fabsf(A[n] - (n + 1) * A[0]) <= 1e-4f * (float)(n + 1));
  const bool fast = (__ballot(fastl) == ~0ull);

  const int base = b * 2048 + chunk * 128;
  const u16* dtp = dt + (size_t)base * 4096 + d;
  const u16* up = ub + (size_t)base * 4096 + d;
  const float* Bp = ssmp + (size_t)base * 256 + 128;  // wave-uniform

  float s[16] = {};
  float dtsum = 0.f;
  float cdt[8], cu[8], ndt[8] = {}, nu[8] = {};
#pragma unroll
  for (int j = 0; j < 8; ++j) {
    cdt[j] = bf2f(dtp[j * 4096]);
    cu[j] = bf2f(up[j * 4096]);
  }
  for (int l0 = 0; l0 < 128; l0 += 8) {
    if (l0 + 8 < 128) {
      int o = (l0 + 8) * 4096;
#pragma unroll
      for (int j = 0; j < 8; ++j) {
        ndt[j] = bf2f(dtp[o + j * 4096]);
        nu[j] = bf2f(up[o + j * 4096]);
      }
    }
    if (fast) {
#pragma unroll
      for (int j = 0; j < 8; ++j) {
        float e1 = __expf(cdt[j] * A[0]);
        float x = cdt[j] * cu[j];
        const float* Bl = Bp + (l0 + j) * 256;
        f32x4 B0 = *(const f32x4*)(Bl);
        f32x4 B1 = *(const f32x4*)(Bl + 4);
        f32x4 B2 = *(const f32x4*)(Bl + 8);
        f32x4 B3 = *(const f32x4*)(Bl + 12);
        float p = 1.f;
#pragma unroll
        for (int n = 0; n < 16; ++n) {
          p *= e1;
          float Bn = (n < 4) ? B0[n & 3] : (n < 8) ? B1[n & 3] : (n < 12) ? B2[n & 3] : B3[n & 3];
          s[n] = fmaf(p, s[n], x * Bn);
        }
        dtsum += cdt[j];
      }
    } else {
#pragma unroll
      for (int j = 0; j < 8; ++j) {
        float x = cdt[j] * cu[j];
        const float* Bl = Bp + (l0 + j) * 256;
        f32x4 B0 = *(const f32x4*)(Bl);
        f32x4 B1 = *(const f32x4*)(Bl + 4);
        f32x4 B2 = *(const f32x4*)(Bl + 8);
        f32x4 B3 = *(const f32x4*)(Bl + 12);
#pragma unroll
        for (int n = 0; n < 16; ++n) {
          float e = __expf(cdt[j] * A[n]);
          float Bn = (n < 4) ? B0[n & 3] : (n < 8) ? B1[n & 3] : (n < 12) ? B2[n & 3] : B3[n & 3];
          s[n] = fmaf(e, s[n], x * Bn);
        }
        dtsum += cdt[j];
      }
    }
#pragma unroll
    for (int j = 0; j < 8; ++j) { cdt[j] = ndt[j]; cu[j] = nu[j]; }
  }
  // summary layout: [b][chunk][n][d] (coalesced in d)
  size_t o = ((size_t)(b * 16 + chunk) * 16) * 4096 + d;
#pragma unroll
  for (int n = 0; n < 16; ++n) {
    Pout[o + (size_t)n * 4096] = __expf(dtsum * A[n]);
    Sout[o + (size_t)n * 4096] = s[n];
  }
}

__global__ __launch_bounds__(256) void scan_y(
    const u16* __restrict__ dt, const u16* __restrict__ ub,
    const float* __restrict__ ssmp, const u16* __restrict__ gs,
    const float* __restrict__ Alog, const float* __restrict__ Dv,
    const float* __restrict__ Pin, const float* __restrict__ Sin,
    u16* __restrict__ yb) {
  const int tid = threadIdx.x;
  const int chunk = blockIdx.x, dgrp = blockIdx.y, b = blockIdx.z;
  const int d = (dgrp << 8) + tid;
  float A[16];
#pragma unroll
  for (int q = 0; q < 4; ++q) {
    f32x4 v = *(const f32x4*)(Alog + d * 16 + q * 4);
    A[q * 4 + 0] = -__expf(v[0]);
    A[q * 4 + 1] = -__expf(v[1]);
    A[q * 4 + 2] = -__expf(v[2]);
    A[q * 4 + 3] = -__expf(v[3]);
  }
  bool fastl = true;
#pragma unroll
  for (int n = 1; n < 16; ++n)
    fastl = fastl && (fabsf(A[n] - (n + 1) * A[0]) <= 1e-4f * (float)(n + 1));
  const bool fast = (__ballot(fastl) == ~0ull);
  const float Dd = Dv[d];

  const int base = b * 2048 + chunk * 128;
  const u16* dtp = dt + (size_t)base * 4096 + d;
  const u16* up = ub + (size_t)base * 4096 + d;
  const u16* gp = gs + (size_t)base * 4096 + d;
  const float* Bp = ssmp + (size_t)base * 256 + 128;
  u16* yo = yb + (size_t)base * 4096 + d;

  // fold prior chunk summaries ([b][chunk][n][d], coalesced in d)
  float s[16] = {};
  {
    for (int k = 0; k < chunk; ++k) {
      size_t o = ((size_t)(b * 16 + k) * 16) * 4096 + d;
#pragma unroll
      for (int n = 0; n < 16; ++n) {
        float P = Pin[o + (size_t)n * 4096];
        float S = Sin[o + (size_t)n * 4096];
        s[n] = fmaf(P, s[n], S);
      }
    }
  }

  float cdt[8], cu[8], cg[8], ndt[8] = {}, nu[8] = {}, ng[8] = {};
#pragma unroll
  for (int j = 0; j < 8; ++j) {
    cdt[j] = bf2f(dtp[j * 4096]);
    cu[j] = bf2f(up[j * 4096]);
    cg[j] = bf2f(gp[j * 4096]);
  }
  for (int l0 = 0; l0 < 128; l0 += 8) {
    if (l0 + 8 < 128) {
      int o = (l0 + 8) * 4096;
#pragma unroll
      for (int j = 0; j < 8; ++j) {
        ndt[j] = bf2f(dtp[o + j * 4096]);
        nu[j] = bf2f(up[o + j * 4096]);
        ng[j] = bf2f(gp[o + j * 4096]);
      }
    }
    if (fast) {
#pragma unroll
      for (int j = 0; j < 8; ++j) {
        float e1 = __expf(cdt[j] * A[0]);
        float x = cdt[j] * cu[j];
        const float* Bl = Bp + (l0 + j) * 256;
        f32x4 B0 = *(const f32x4*)(Bl);
        f32x4 B1 = *(const f32x4*)(Bl + 4);
        f32x4 B2 = *(const f32x4*)(Bl + 8);
        f32x4 B3 = *(const f32x4*)(Bl + 12);
        f32x4 C0 = *(const f32x4*)(Bl + 16);
        f32x4 C1 = *(const f32x4*)(Bl + 20);
        f32x4 C2 = *(const f32x4*)(Bl + 24);
        f32x4 C3 = *(const f32x4*)(Bl + 28);
        float p = 1.f;
        float y0 = 0.f, y1 = 0.f, y2 = 0.f, y3 = 0.f;
#pragma unroll
        for (int n = 0; n < 16; ++n) {
          p *= e1;
          float Bn = (n < 4) ? B0[n & 3] : (n < 8) ? B1[n & 3] : (n < 12) ? B2[n & 3] : B3[n & 3];
          float Cn = (n < 4) ? C0[n & 3] : (n < 8) ? C1[n & 3] : (n < 12) ? C2[n & 3] : C3[n & 3];
          s[n] = fmaf(p, s[n], x * Bn);
          if (n < 4) y0 = fmaf(s[n], Cn, y0);
          else if (n < 8) y1 = fmaf(s[n], Cn, y1);
          else if (n < 12) y2 = fmaf(s[n], Cn, y2);
          else y3 = fmaf(s[n], Cn, y3);
        }
        float y = (y0 + y1) + (y2 + y3);
        yo[(l0 + j) * 4096] = f2bf((y + cu[j] * Dd) * cg[j]);
      }
    } else {
#pragma unroll
      for (int j = 0; j < 8; ++j) {
        float x = cdt[j] * cu[j];
        const float* Bl = Bp + (l0 + j) * 256;
        f32x4 B0 = *(const f32x4*)(Bl);
        f32x4 B1 = *(const f32x4*)(Bl + 4);
        f32x4 B2 = *(const f32x4*)(Bl + 8);
        f32x4 B3 = *(const f32x4*)(Bl + 12);
        f32x4 C0 = *(const f32x4*)(Bl + 16);
        f32x4 C1 = *(const f32x4*)(Bl + 20);
        f32x4 C2 = *(const f32x4*)(Bl + 24);
        f32x4 C3 = *(const f32x4*)(Bl + 28);
        float y0 = 0.f, y1 = 0.f, y2 = 0.f, y3 = 0.f;
#pragma unroll
        for (int n = 0; n < 16; ++n) {
          float e = __expf(cdt[j] * A[n]);
          float Bn = (n < 4) ? B0[n & 3] : (n < 8) ? B1[n & 3] : (n < 12) ? B2[n & 3] : B3[n & 3];
          float Cn = (n < 4) ? C0[n & 3] : (n < 8) ? C1[n & 3] : (n < 12) ? C2[n & 3] : C3[n & 3];
          s[n] = fmaf(e, s[n], x * Bn);
          if (n < 4) y0 = fmaf(s[n], Cn, y0);
          else if (n < 8) y1 = fmaf(s[n], Cn, y1);
          else if (n < 12) y2 = fmaf(s[n], Cn, y2);
          else y3 = fmaf(s[n], Cn, y3);
        }
        float y = (y0 + y1) + (y2 + y3);
        yo[(l0 + j) * 4096] = f2bf((y + cu[j] * Dd) * cg[j]);
      }
    }
#pragma unroll
    for (int j = 0; j < 8; ++j) { cdt[j] = ndt[j]; cu[j] = nu[j]; cg[j] = ng[j]; }
  }
}

extern "C" void kernel_launch(void* const* d_in, const int* in_sizes, int n_in,
                              void* d_out, int out_size, void* d_ws,
                              size_t ws_size, hipStream_t stream) {
  (void)in_sizes; (void)n_in; (void)out_size; (void)ws_size;
  const float* hs = (const float*)d_in[0];    // (2,2048,2048)
  const float* wIn = (const float*)d_in[1];   // (8192,2048)
  const float* cw = (const float*)d_in[2];    // (4096,1,4)
  const float* cb = (const float*)d_in[3];    // (4096)
  const float* wX = (const float*)d_in[4];    // (160,4096)
  const float* wDt = (const float*)d_in[5];   // (4096,128)
  const float* bDt = (const float*)d_in[6];   // (4096)
  const float* Alog = (const float*)d_in[7];  // (4096,16)
  const float* Dv = (const float*)d_in[8];    // (4096)
  const float* wOut = (const float*)d_in[9];  // (2048,4096)

  // ---- workspace layout (byte offsets, peak 184 MB) -----------------------
  // Xb[0,16M) Winb[16,48M) dead after in_proj; Pu[48,80) dead after conv;
  // Dtb bf16 [0,32M) over Xb/Winb-head; Yb[64,96) over Pu tail;
  // Ub[96,128) Wxb[128,130) Smp[130,134) Dtrb[134,135) Wdtb[135,136)
  // Wob[136,152) Pchk[152,160) Schk[160,168) Xpart[168,184).
  // Pg (silu gate bf16) lives in d_out until out_proj overwrites it.
  const size_t MB = 1ull << 20;
  char* w = (char*)d_ws;
  u16* Xb = (u16*)(w + 0 * MB);
  u16* Winb = (u16*)(w + 16 * MB);
  u16* Pu = (u16*)(w + 48 * MB);
  u16* Dtb = (u16*)(w + 0 * MB);
  u16* Yb = (u16*)(w + 64 * MB);
  u16* Ub = (u16*)(w + 96 * MB);
  u16* Wxb = (u16*)(w + 128 * MB);
  float* Smp = (float*)(w + 130 * MB);
  u16* Dtrb = (u16*)(w + 134 * MB);
  u16* Wdtb = (u16*)(w + 135 * MB);
  u16* Wob = (u16*)(w + 136 * MB);
  float* Pchk = (float*)(w + 152 * MB);
  float* Schk = (float*)(w + 160 * MB);
  float* Xpart = (float*)(w + 168 * MB);
  u16* Pg = (u16*)d_out;

  // step 1: all fp32->bf16 converts in one dispatch
  cvt_all<<<34304, 256, 0, stream>>>(hs, wIn, wOut, wDt, wX, Xb, Winb, Wob, Wdtb, Wxb);
  // step 2: in_proj, single dispatch (u plain bf16 | gate silu bf16)
  gemm_bt<5><<<dim3(64, 32), 256, 0, stream>>>(Xb, Winb, Pu, (const float*)Pg, 2048, 4096);
  // step 3: depthwise conv + silu
  conv_silu<<<16384, 256, 0, stream>>>(Pu, cw, cb, Ub);
  // step 4: x_proj split-K x4 into partials, then reduce (+ dt_r extract)
  gemm_bt<0, true><<<dim3(2, 32, 4), 256, 0, stream>>>(Ub, Wxb, Xpart, nullptr, 4096, 256);
  xp_reduce<<<1024, 256, 0, stream>>>(Xpart, Smp, Dtrb);
  // step 5: dt_proj with fused softplus(acc + bias) -> bf16 dt
  gemm_bt<4><<<dim3(32, 32), 256, 0, stream>>>(Dtrb, Wdtb, Dtb, bDt, 128, 4096);
  // step 6: chunked selective scan (pass 1: summaries, pass 2: y)
  scan_part<<<dim3(16, 16, 2), 256, 0, stream>>>(Dtb, Ub, Smp, Alog, Pchk, Schk);
  scan_y<<<dim3(16, 16, 2), 256, 0, stream>>>(Dtb, Ub, Smp, Pg, Alog, Dv, Pchk, Schk, Yb);
  // step 7: out_proj -> fp32 output (overwrites Pg/d_out entirely)
  gemm_bt<0><<<dim3(16, 32), 256, 0, stream>>>(Yb, Wob, (float*)d_out, nullptr, 4096, 2048);
}

// Round 9
// 647.738 us; speedup vs baseline: 3.1053x; 1.0299x over previous
//
#include <hip/hip_runtime.h>

typedef unsigned int u32;
typedef unsigned short u16;
typedef float f32x4 __attribute__((ext_vector_type(4)));
typedef float f32x16 __attribute__((ext_vector_type(16)));
typedef u16 us4 __attribute__((ext_vector_type(4)));
typedef u16 us8 __attribute__((ext_vector_type(8)));
typedef __bf16 bf16x8 __attribute__((ext_vector_type(8)));

__device__ __forceinline__ u16 f2bf(float f) {
  u32 u = __builtin_bit_cast(u32, f);
  u += 0x7fffu + ((u >> 16) & 1u);
  return (u16)(u >> 16);
}
__device__ __forceinline__ float bf2f(u16 h) {
  u32 u = ((u32)h) << 16;
  return __builtin_bit_cast(float, u);
}
__device__ __forceinline__ void async16(const void* g, void* l) {
  __builtin_amdgcn_global_load_lds((const __attribute__((address_space(1))) void*)g,
                                   (__attribute__((address_space(3))) void*)l, 16, 0, 0);
}

// ---------------------------------------------------------------------------
// C = A * B^T.  A: M x K bf16 row-major. B: N x K bf16 row-major.
// BK=64, XOR-8 swizzled LDS (conflict-free, verified r7), 32x32x16 MFMA
// (higher ceiling + half the MFMA issue slots vs 16x16x32 — m119 vs m06).
// A/B frag: [m|n = lane&31][k = 8*(lane>>5) + j]; C/D: col=lane&31,
// row=(reg&3)+8*(reg>>2)+4*(lane>>5)  [m74/m101].
// ACT: 0 fp32, 1 bf16, 2 bf16 silu, 3 fp32 softplus(+bias),
// 4 bf16 softplus(+bias), 5 in_proj dual (col<4096 bf16->Cv, else silu bf16
// into `bias` as u16*).  SPLITK: blockIdx.z K-slice, C offset per z.
// ---------------------------------------------------------------------------
template <int ACT, bool SPLITK = false>
__global__ __launch_bounds__(256) void gemm_bt(const u16* __restrict__ A,
                                               const u16* __restrict__ B,
                                               void* __restrict__ Cv,
                                               const float* __restrict__ bias,
                                               int K, int ldc) {
  __shared__ __align__(16) u16 As[128 * 64];
  __shared__ __align__(16) u16 Bs[128 * 64];
  const int tid = threadIdx.x;
  const int lane = tid & 63;
  const int wave = tid >> 6;
  const int ln = lane & 31;   // m/n within 32-tile
  const int hw = lane >> 5;   // half-wave k selector
  const int wm = (wave >> 1) << 6;
  const int wn = (wave & 1) << 6;
  const long rowBase = (long)blockIdx.y << 7;
  const long colBase = (long)blockIdx.x << 7;

  int kStart = 0, kEnd = K;
  if constexpr (SPLITK) {
    int kn = K / gridDim.z;
    kStart = blockIdx.z * kn;
    kEnd = kStart + kn;
  }

  const int rr = tid >> 3;
  const int qg = (tid & 7) ^ (rr & 7);
  const u16* Ag = A + (rowBase + rr) * (long)K + qg * 8;
  const u16* Bg = B + (colBase + rr) * (long)K + qg * 8;
  u16* Al = As + tid * 8;
  u16* Bl = Bs + tid * 8;

  f32x16 acc[2][2] = {};
  const int l7 = ln & 7;

  for (int k0 = kStart; k0 < kEnd; k0 += 64) {
#pragma unroll
    for (int c = 0; c < 4; ++c) {
      async16(Ag + 32L * c * K + k0, Al + 2048 * c);
      async16(Bg + 32L * c * K + k0, Bl + 2048 * c);
    }
    __syncthreads();
#pragma unroll
    for (int s = 0; s < 4; ++s) {  // K=16 slice; chunk pair {2s, 2s+1}
      const int xa = ((s * 2 + hw) ^ l7) * 8;
      us8 af[2], bfr[2];
#pragma unroll
      for (int i = 0; i < 2; ++i)
        af[i] = *(const us8*)(As + (wm + i * 32 + ln) * 64 + xa);
#pragma unroll
      for (int i = 0; i < 2; ++i)
        bfr[i] = *(const us8*)(Bs + (wn + i * 32 + ln) * 64 + xa);
#pragma unroll
      for (int i = 0; i < 2; ++i)
#pragma unroll
        for (int j = 0; j < 2; ++j)
          acc[i][j] = __builtin_amdgcn_mfma_f32_32x32x16_bf16(
              __builtin_bit_cast(bf16x8, af[i]), __builtin_bit_cast(bf16x8, bfr[j]),
              acc[i][j], 0, 0, 0);
    }
    __syncthreads();
  }

  float* Cf = (float*)Cv;
  if constexpr (SPLITK)
    Cf += (size_t)blockIdx.z * ((size_t)gridDim.y * 128 * ldc);

#pragma unroll
  for (int i = 0; i < 2; ++i)
#pragma unroll
    for (int j = 0; j < 2; ++j)
#pragma unroll
      for (int r = 0; r < 16; ++r) {
        long row = rowBase + wm + i * 32 + (r & 3) + 8 * (r >> 2) + 4 * hw;
        long col = colBase + wn + j * 32 + ln;
        float v = acc[i][j][r];
        if constexpr (ACT == 0) {
          Cf[row * ldc + col] = v;
        } else if constexpr (ACT == 1) {
          ((u16*)Cv)[row * ldc + col] = f2bf(v);
        } else if constexpr (ACT == 2) {
          float s = v / (1.f + __expf(-v));
          ((u16*)Cv)[row * ldc + col] = f2bf(s);
        } else if constexpr (ACT == 3) {
          v += bias[col];
          float sp = (v > 20.f) ? v : log1pf(__expf(v));
          Cf[row * ldc + col] = sp;
        } else if constexpr (ACT == 4) {
          v += bias[col];
          float sp = (v > 20.f) ? v : log1pf(__expf(v));
          ((u16*)Cv)[row * ldc + col] = f2bf(sp);
        } else {  // ACT == 5
          if (colBase < 4096) {
            ((u16*)Cv)[row * 4096 + col] = f2bf(v);
          } else {
            float s = v / (1.f + __expf(-v));
            ((u16*)(size_t)bias)[row * 4096 + (col - 4096)] = f2bf(s);
          }
        }
      }
}

// one fused fp32->bf16 convert for all weight/input tensors
__device__ __forceinline__ void cvt4(const float* __restrict__ in,
                                     u16* __restrict__ out, int i) {
  f32x4 v = ((const f32x4*)in)[i];
  us4 o;
  o[0] = f2bf(v[0]); o[1] = f2bf(v[1]); o[2] = f2bf(v[2]); o[3] = f2bf(v[3]);
  ((us4*)out)[i] = o;
}
__global__ __launch_bounds__(256) void cvt_all(
    const float* __restrict__ hs, const float* __restrict__ wIn,
    const float* __restrict__ wOut, const float* __restrict__ wDt,
    const float* __restrict__ wX, u16* __restrict__ Xb, u16* __restrict__ Winb,
    u16* __restrict__ Wob, u16* __restrict__ Wdtb, u16* __restrict__ Wxb) {
  int i = blockIdx.x * 256 + threadIdx.x;
  if (i < 2097152) { cvt4(hs, Xb, i); return; }
  i -= 2097152;
  if (i < 4194304) { cvt4(wIn, Winb, i); return; }
  i -= 4194304;
  if (i < 2097152) { cvt4(wOut, Wob, i); return; }
  i -= 2097152;
  if (i < 131072) { cvt4(wDt, Wdtb, i); return; }
  i -= 131072;
  if (i >= 262144) return;
  int row = (i << 2) >> 12;
  us4 o;
  if (row < 160) {
    f32x4 v = ((const f32x4*)wX)[i];
    o[0] = f2bf(v[0]); o[1] = f2bf(v[1]); o[2] = f2bf(v[2]); o[3] = f2bf(v[3]);
  } else {
    o[0] = 0; o[1] = 0; o[2] = 0; o[3] = 0;
  }
  ((us4*)Wxb)[i] = o;
}

// reduce 4 split-K partials of x_proj -> Smp fp32 (4096 x 256); also emit
// dt_r bf16 (first 128 cols).
__global__ __launch_bounds__(256) void xp_reduce(const float* __restrict__ part,
                                                 float* __restrict__ smp,
                                                 u16* __restrict__ dtrb) {
  int i = blockIdx.x * 256 + threadIdx.x;
  const f32x4* p = (const f32x4*)part;
  f32x4 v = p[i];
  v += p[i + 262144];
  v += p[i + 524288];
  v += p[i + 786432];
  ((f32x4*)smp)[i] = v;
  int e = i << 2;
  int c = e & 255;
  if (c < 128) {
    int t = e >> 8;
    us4 o;
    o[0] = f2bf(v[0]); o[1] = f2bf(v[1]); o[2] = f2bf(v[2]); o[3] = f2bf(v[3]);
    *(us4*)(dtrb + t * 128 + c) = o;
  }
}

// depthwise causal conv (K=4) + bias + SiLU
__global__ __launch_bounds__(256) void conv_silu(const u16* __restrict__ U,
                                                 const float* __restrict__ cw,
                                                 const float* __restrict__ cb,
                                                 u16* __restrict__ out) {
  int i = blockIdx.x * 256 + threadIdx.x;
  int t = i >> 10;
  int d4 = (i & 1023) << 2;
  int l = t & 2047;
  float w[4][4];
#pragma unroll
  for (int j = 0; j < 4; ++j) {
    f32x4 wv = *(const f32x4*)(cw + (d4 + j) * 4);
    w[j][0] = wv[0]; w[j][1] = wv[1]; w[j][2] = wv[2]; w[j][3] = wv[3];
  }
  float r[4] = {cb[d4], cb[d4 + 1], cb[d4 + 2], cb[d4 + 3]};
#pragma unroll
  for (int k = 0; k < 4; ++k) {
    int ll = l - 3 + k;
    if (ll >= 0) {
      us4 xv = *(const us4*)(U + (size_t)(t - 3 + k) * 4096 + d4);
      r[0] += w[0][k] * bf2f(xv[0]);
      r[1] += w[1][k] * bf2f(xv[1]);
      r[2] += w[2][k] * bf2f(xv[2]);
      r[3] += w[3][k] * bf2f(xv[3]);
    }
  }
  us4 o;
#pragma unroll
  for (int j = 0; j < 4; ++j) {
    float v = r[j];
    float s = v / (1.f + __expf(-v));
    o[j] = f2bf(s);
  }
  *(us4*)(out + (size_t)t * 4096 + d4) = o;
}

// ---------------------------------------------------------------------------
// Chunked selective scan, 32 chunks of 64 steps, channel-per-thread.
// scan_part: per-chunk partial state S (from 0) + dtsum (P = exp(dtsum*A)
// reconstructed later — saves 15/16 of P storage).
// scan_fold: serial prefix over chunks -> per-chunk initial states Sinit.
// scan_y: starts from Sinit, no fold (removes the quadratic re-read).
// Summary layout [b][chunk][n][d] (coalesced in d).
// ---------------------------------------------------------------------------
__global__ __launch_bounds__(256) void scan_part(
    const u16* __restrict__ dt, const u16* __restrict__ ub,
    const float* __restrict__ ssmp, const float* __restrict__ Alog,
    float* __restrict__ Sout, float* __restrict__ dtsumo) {
  const int tid = threadIdx.x;
  const int chunk = blockIdx.x, dgrp = blockIdx.y, b = blockIdx.z;
  const int d = (dgrp << 8) + tid;
  float A[16];
#pragma unroll
  for (int q = 0; q < 4; ++q) {
    f32x4 v = *(const f32x4*)(Alog + d * 16 + q * 4);
    A[q * 4 + 0] = -__expf(v[0]);
    A[q * 4 + 1] = -__expf(v[1]);
    A[q * 4 + 2] = -__expf(v[2]);
    A[q * 4 + 3] = -__expf(v[3]);
  }
  bool fastl = true;
#pragma unroll
  for (int n = 1; n < 16; ++n)
    fastl = fastl && (fabsf(A[n] - (n + 1) * A[0]) <= 1e-4f * (float)(n + 1));
  const bool fast = (__ballot(fastl) == ~0ull);

  const int base = b * 2048 + chunk * 64;
  const u16* dtp = dt + (size_t)base * 4096 + d;
  const u16* up = ub + (size_t)base * 4096 + d;
  const float* Bp = ssmp + (size_t)base * 256 + 128;

  float s[16] = {};
  float dtsum = 0.f;
  float cdt[8], cu[8], ndt[8] = {}, nu[8] = {};
#pragma unroll
  for (int j = 0; j < 8; ++j) {
    cdt[j] = bf2f(dtp[j * 4096]);
    cu[j] = bf2f(up[j * 4096]);
  }
  for (int l0 = 0; l0 < 64; l0 += 8) {
    if (l0 + 8 < 64) {
      int o = (l0 + 8) * 4096;
#pragma unroll
      for (int j = 0; j < 8; ++j) {
        ndt[j] = bf2f(dtp[o + j * 4096]);
        nu[j] = bf2f(up[o + j * 4096]);
      }
    }
    if (fast) {
#pragma unroll
      for (int j = 0; j < 8; ++j) {
        float e1 = __expf(cdt[j] * A[0]);
        float x = cdt[j] * cu[j];
        const float* Bl = Bp + (l0 + j) * 256;
        f32x4 B0 = *(const f32x4*)(Bl);
        f32x4 B1 = *(const f32x4*)(Bl + 4);
        f32x4 B2 = *(const f32x4*)(Bl + 8);
        f32x4 B3 = *(const f32x4*)(Bl + 12);
        float p = 1.f;
#pragma unroll
        for (int n = 0; n < 16; ++n) {
          p *= e1;
          float Bn = (n < 4) ? B0[n & 3] : (n < 8) ? B1[n & 3] : (n < 12) ? B2[n & 3] : B3[n & 3];
          s[n] = fmaf(p, s[n], x * Bn);
        }
        dtsum += cdt[j];
      }
    } else {
#pragma unroll
      for (int j = 0; j < 8; ++j) {
        float x = cdt[j] * cu[j];
        const float* Bl = Bp + (l0 + j) * 256;
        f32x4 B0 = *(const f32x4*)(Bl);
        f32x4 B1 = *(const f32x4*)(Bl + 4);
        f32x4 B2 = *(const f32x4*)(Bl + 8);
        f32x4 B3 = *(const f32x4*)(Bl + 12);
#pragma unroll
        for (int n = 0; n < 16; ++n) {
          float e = __expf(cdt[j] * A[n]);
          float Bn = (n < 4) ? B0[n & 3] : (n < 8) ? B1[n & 3] : (n < 12) ? B2[n & 3] : B3[n & 3];
          s[n] = fmaf(e, s[n], x * Bn);
        }
        dtsum += cdt[j];
      }
    }
#pragma unroll
    for (int j = 0; j < 8; ++j) { cdt[j] = ndt[j]; cu[j] = nu[j]; }
  }
  size_t o = ((size_t)(b * 32 + chunk) * 16) * 4096 + d;
#pragma unroll
  for (int n = 0; n < 16; ++n) Sout[o + (size_t)n * 4096] = s[n];
  dtsumo[(size_t)(b * 32 + chunk) * 4096 + d] = dtsum;
}

// prefix-fold chunk summaries: thread = (b, n, d); 32 serial chunks.
__global__ __launch_bounds__(256) void scan_fold(
    const float* __restrict__ Sin, const float* __restrict__ dtsum,
    const float* __restrict__ Alog, float* __restrict__ Sinit) {
  const int tid = threadIdx.x;
  const int n = blockIdx.x, dgrp = blockIdx.y, b = blockIdx.z;
  const int d = (dgrp << 8) + tid;
  const float A = -__expf(Alog[d * 16 + n]);
  float run = 0.f;
  for (int c = 0; c < 32; ++c) {
    size_t o = ((size_t)(b * 32 + c) * 16 + n) * 4096 + d;
    Sinit[o] = run;
    float P = __expf(dtsum[(size_t)(b * 32 + c) * 4096 + d] * A);
    run = fmaf(P, run, Sin[o]);
  }
}

__global__ __launch_bounds__(256) void scan_y(
    const u16* __restrict__ dt, const u16* __restrict__ ub,
    const float* __restrict__ ssmp, const u16* __restrict__ gs,
    const float* __restrict__ Alog, const float* __restrict__ Dv,
    const float* __restrict__ Sinit, u16* __restrict__ yb) {
  const int tid = threadIdx.x;
  const int chunk = blockIdx.x, dgrp = blockIdx.y, b = blockIdx.z;
  const int d = (dgrp << 8) + tid;
  float A[16];
#pragma unroll
  for (int q = 0; q < 4; ++q) {
    f32x4 v = *(const f32x4*)(Alog + d * 16 + q * 4);
    A[q * 4 + 0] = -__expf(v[0]);
    A[q * 4 + 1] = -__expf(v[1]);
    A[q * 4 + 2] = -__expf(v[2]);
    A[q * 4 + 3] = -__expf(v[3]);
  }
  bool fastl = true;
#pragma unroll
  for (int n = 1; n < 16; ++n)
    fastl = fastl && (fabsf(A[n] - (n + 1) * A[0]) <= 1e-4f * (float)(n + 1));
  const bool fast = (__ballot(fastl) == ~0ull);
  const float Dd = Dv[d];

  const int base = b * 2048 + chunk * 64;
  const u16* dtp = dt + (size_t)base * 4096 + d;
  const u16* up = ub + (size_t)base * 4096 + d;
  const u16* gp = gs + (size_t)base * 4096 + d;
  const float* Bp = ssmp + (size_t)base * 256 + 128;
  u16* yo = yb + (size_t)base * 4096 + d;

  float s[16];
  {
    size_t o = ((size_t)(b * 32 + chunk) * 16) * 4096 + d;
#pragma unroll
    for (int n = 0; n < 16; ++n) s[n] = Sinit[o + (size_t)n * 4096];
  }

  float cdt[8], cu[8], cg[8], ndt[8] = {}, nu[8] = {}, ng[8] = {};
#pragma unroll
  for (int j = 0; j < 8; ++j) {
    cdt[j] = bf2f(dtp[j * 4096]);
    cu[j] = bf2f(up[j * 4096]);
    cg[j] = bf2f(gp[j * 4096]);
  }
  for (int l0 = 0; l0 < 64; l0 += 8) {
    if (l0 + 8 < 64) {
      int o = (l0 + 8) * 4096;
#pragma unroll
      for (int j = 0; j < 8; ++j) {
        ndt[j] = bf2f(dtp[o + j * 4096]);
        nu[j] = bf2f(up[o + j * 4096]);
        ng[j] = bf2f(gp[o + j * 4096]);
      }
    }
    if (fast) {
#pragma unroll
      for (int j = 0; j < 8; ++j) {
        float e1 = __expf(cdt[j] * A[0]);
        float x = cdt[j] * cu[j];
        const float* Bl = Bp + (l0 + j) * 256;
        f32x4 B0 = *(const f32x4*)(Bl);
        f32x4 B1 = *(const f32x4*)(Bl + 4);
        f32x4 B2 = *(const f32x4*)(Bl + 8);
        f32x4 B3 = *(const f32x4*)(Bl + 12);
        f32x4 C0 = *(const f32x4*)(Bl + 16);
        f32x4 C1 = *(const f32x4*)(Bl + 20);
        f32x4 C2 = *(const f32x4*)(Bl + 24);
        f32x4 C3 = *(const f32x4*)(Bl + 28);
        float p = 1.f;
        float y0 = 0.f, y1 = 0.f, y2 = 0.f, y3 = 0.f;
#pragma unroll
        for (int n = 0; n < 16; ++n) {
          p *= e1;
          float Bn = (n < 4) ? B0[n & 3] : (n < 8) ? B1[n & 3] : (n < 12) ? B2[n & 3] : B3[n & 3];
          float Cn = (n < 4) ? C0[n & 3] : (n < 8) ? C1[n & 3] : (n < 12) ? C2[n & 3] : C3[n & 3];
          s[n] = fmaf(p, s[n], x * Bn);
          if (n < 4) y0 = fmaf(s[n], Cn, y0);
          else if (n < 8) y1 = fmaf(s[n], Cn, y1);
          else if (n < 12) y2 = fmaf(s[n], Cn, y2);
          else y3 = fmaf(s[n], Cn, y3);
        }
        float y = (y0 + y1) + (y2 + y3);
        yo[(l0 + j) * 4096] = f2bf((y + cu[j] * Dd) * cg[j]);
      }
    } else {
#pragma unroll
      for (int j = 0; j < 8; ++j) {
        float x = cdt[j] * cu[j];
        const float* Bl = Bp + (l0 + j) * 256;
        f32x4 B0 = *(const f32x4*)(Bl);
        f32x4 B1 = *(const f32x4*)(Bl + 4);
        f32x4 B2 = *(const f32x4*)(Bl + 8);
        f32x4 B3 = *(const f32x4*)(Bl + 12);
        f32x4 C0 = *(const f32x4*)(Bl + 16);
        f32x4 C1 = *(const f32x4*)(Bl + 20);
        f32x4 C2 = *(const f32x4*)(Bl + 24);
        f32x4 C3 = *(const f32x4*)(Bl + 28);
        float y0 = 0.f, y1 = 0.f, y2 = 0.f, y3 = 0.f;
#pragma unroll
        for (int n = 0; n < 16; ++n) {
          float e = __expf(cdt[j] * A[n]);
          float Bn = (n < 4) ? B0[n & 3] : (n < 8) ? B1[n & 3] : (n < 12) ? B2[n & 3] : B3[n & 3];
          float Cn = (n < 4) ? C0[n & 3] : (n < 8) ? C1[n & 3] : (n < 12) ? C2[n & 3] : C3[n & 3];
          s[n] = fmaf(e, s[n], x * Bn);
          if (n < 4) y0 = fmaf(s[n], Cn, y0);
          else if (n < 8) y1 = fmaf(s[n], Cn, y1);
          else if (n < 12) y2 = fmaf(s[n], Cn, y2);
          else y3 = fmaf(s[n], Cn, y3);
        }
        float y = (y0 + y1) + (y2 + y3);
        yo[(l0 + j) * 4096] = f2bf((y + cu[j] * Dd) * cg[j]);
      }
    }
#pragma unroll
    for (int j = 0; j < 8; ++j) { cdt[j] = ndt[j]; cu[j] = nu[j]; cg[j] = ng[j]; }
  }
}

extern "C" void kernel_launch(void* const* d_in, const int* in_sizes, int n_in,
                              void* d_out, int out_size, void* d_ws,
                              size_t ws_size, hipStream_t stream) {
  (void)in_sizes; (void)n_in; (void)out_size; (void)ws_size;
  const float* hs = (const float*)d_in[0];
  const float* wIn = (const float*)d_in[1];
  const float* cw = (const float*)d_in[2];
  const float* cb = (const float*)d_in[3];
  const float* wX = (const float*)d_in[4];
  const float* wDt = (const float*)d_in[5];
  const float* bDt = (const float*)d_in[6];
  const float* Alog = (const float*)d_in[7];
  const float* Dv = (const float*)d_in[8];
  const float* wOut = (const float*)d_in[9];

  // ---- workspace layout (peak 185 MB) -------------------------------------
  // Xb[0,16) Winb[16,48) dead after in_proj; Pu[48,80) dead after conv;
  // Dtb bf16 [0,32); Yb[64,96); Ub[96,128); Wxb[128,130); Smp[130,134);
  // Dtrb[134,135); Wdtb[135,136); Wob[136,152);
  // Schk[152,168)  (Xpart 16MB aliases this — dead before scan_part writes);
  // Sinit[168,184); dtsum[184,185).
  // Pg (silu gate bf16) lives in d_out until out_proj overwrites it.
  const size_t MB = 1ull << 20;
  char* w = (char*)d_ws;
  u16* Xb = (u16*)(w + 0 * MB);
  u16* Winb = (u16*)(w + 16 * MB);
  u16* Pu = (u16*)(w + 48 * MB);
  u16* Dtb = (u16*)(w + 0 * MB);
  u16* Yb = (u16*)(w + 64 * MB);
  u16* Ub = (u16*)(w + 96 * MB);
  u16* Wxb = (u16*)(w + 128 * MB);
  float* Smp = (float*)(w + 130 * MB);
  u16* Dtrb = (u16*)(w + 134 * MB);
  u16* Wdtb = (u16*)(w + 135 * MB);
  u16* Wob = (u16*)(w + 136 * MB);
  float* Schk = (float*)(w + 152 * MB);
  float* Xpart = (float*)(w + 152 * MB);  // alias: dead before Schk written
  float* Sinit = (float*)(w + 168 * MB);
  float* Dtsum = (float*)(w + 184 * MB);
  u16* Pg = (u16*)d_out;

  cvt_all<<<34304, 256, 0, stream>>>(hs, wIn, wOut, wDt, wX, Xb, Winb, Wob, Wdtb, Wxb);
  gemm_bt<5><<<dim3(64, 32), 256, 0, stream>>>(Xb, Winb, Pu, (const float*)Pg, 2048, 4096);
  conv_silu<<<16384, 256, 0, stream>>>(Pu, cw, cb, Ub);
  gemm_bt<0, true><<<dim3(2, 32, 4), 256, 0, stream>>>(Ub, Wxb, Xpart, nullptr, 4096, 256);
  xp_reduce<<<1024, 256, 0, stream>>>(Xpart, Smp, Dtrb);
  gemm_bt<4><<<dim3(32, 32), 256, 0, stream>>>(Dtrb, Wdtb, Dtb, bDt, 128, 4096);
  scan_part<<<dim3(32, 16, 2), 256, 0, stream>>>(Dtb, Ub, Smp, Alog, Schk, Dtsum);
  scan_fold<<<dim3(16, 16, 2), 256, 0, stream>>>(Schk, Dtsum, Alog, Sinit);
  scan_y<<<dim3(32, 16, 2), 256, 0, stream>>>(Dtb, Ub, Smp, Pg, Alog, Dv, Sinit, Yb);
  gemm_bt<0><<<dim3(16, 32), 256, 0, stream>>>(Yb, Wob, (float*)d_out, nullptr, 4096, 2048);
}